// Round 1
// baseline (8451.193 us; speedup 1.0000x reference)
//
#include <hip/hip_runtime.h>
#include <math.h>

#define FBINS 513
#define HDIM  1026
#define LENN  1024
#define BATCH 32
#define CHAN  128
#define NEXP  8
#define MROWS 4096   // BATCH*CHAN

// ---------------------------------------------------------------------------
// Table generation: forward DFT matrix (rows 0..512 = cos, rows 513..1025 = -sin),
// inverse matrices Finv_c[t][f] = c_f*cos(2pi f t/N)/N, Finv_s[t][f] = -c_f*sin(...)/N
// ---------------------------------------------------------------------------
__global__ void gen_tables(float* __restrict__ Ffwd, float* __restrict__ Finv_c,
                           float* __restrict__ Finv_s) {
    long i = (long)blockIdx.x * 256 + threadIdx.x;
    const long nF = (long)HDIM * LENN;       // 1026*1024
    const long nI = (long)LENN * FBINS;      // 1024*513
    const float TWO_PI = 6.283185307179586f;
    if (i < nF) {
        int n = (int)(i / LENN), t = (int)(i % LENN);
        int f = (n < FBINS) ? n : (n - FBINS);
        int k = (f * t) & (LENN - 1);
        float s, c;
        sincosf(TWO_PI * (float)k / (float)LENN, &s, &c);
        Ffwd[i] = (n < FBINS) ? c : (-s);
    } else if (i < nF + 2 * nI) {
        long j = i - nF;
        bool is_s = (j >= nI);
        if (is_s) j -= nI;
        int t = (int)(j / FBINS), f = (int)(j % FBINS);
        int k = (f * t) & (LENN - 1);
        float s, c;
        sincosf(TWO_PI * (float)k / (float)LENN, &s, &c);
        float cf = (f == 0 || f == FBINS - 1) ? 1.0f : 2.0f;
        float scale = cf * (1.0f / (float)LENN);
        if (is_s) Finv_s[j] = -s * scale;
        else      Finv_c[j] =  c * scale;
    }
}

// ---------------------------------------------------------------------------
// Bounds prep: sigmoid(7), sort 9, idx = trunc(b*512), write {start,end} pairs
// ---------------------------------------------------------------------------
__global__ void prep_kernel(const float* __restrict__ bp, int* __restrict__ se) {
    if (threadIdx.x == 0 && blockIdx.x == 0) {
        float b[9];
        b[0] = 0.0f; b[8] = 1.0f;
        for (int i = 0; i < 7; i++) b[i + 1] = 1.0f / (1.0f + expf(-bp[i]));
        for (int i = 1; i < 9; i++) {           // insertion sort
            float v = b[i]; int j = i - 1;
            while (j >= 0 && b[j] > v) { b[j + 1] = b[j]; j--; }
            b[j + 1] = v;
        }
        int idx[9];
        for (int i = 0; i < 9; i++) idx[i] = (int)(b[i] * (float)(FBINS - 1));
        for (int e = 0; e < NEXP; e++) {
            se[2 * e]     = idx[e];
            se[2 * e + 1] = (e < NEXP - 1) ? idx[e + 1] : FBINS;
        }
    }
}

// ---------------------------------------------------------------------------
// mag[b][f] = mean_c sqrt(Xr^2 + Xi^2); XrXi layout [4096][1026] (Xr|Xi)
// ---------------------------------------------------------------------------
__global__ void mag_kernel(const float* __restrict__ XrXi, float* __restrict__ mag) {
    int f = blockIdx.x * 256 + threadIdx.x;
    int b = blockIdx.y;
    if (f >= FBINS) return;
    const float* base = XrXi + (long)b * CHAN * HDIM;
    float acc = 0.0f;
    for (int c = 0; c < CHAN; c++) {
        float xr = base[(long)c * HDIM + f];
        float xi = base[(long)c * HDIM + FBINS + f];
        acc += sqrtf(xr * xr + xi * xi);
    }
    mag[b * FBINS + f] = acc * (1.0f / (float)CHAN);
}

// ---------------------------------------------------------------------------
// gate[b][e] = softmax_e( sum_f mag[b][f]*gW[e][f] + gb[e] ); one wave per b
// ---------------------------------------------------------------------------
__global__ void gate_kernel(const float* __restrict__ mag, const float* __restrict__ gW,
                            const float* __restrict__ gb, float* __restrict__ gate) {
    int b = blockIdx.x;
    int lane = threadIdx.x;        // 64
    int e = lane & 7, j = lane >> 3;
    float acc = 0.0f;
    for (int f = j; f < FBINS; f += 8)
        acc += mag[b * FBINS + f] * gW[e * FBINS + f];
    acc += __shfl_xor(acc, 8);
    acc += __shfl_xor(acc, 16);
    acc += __shfl_xor(acc, 32);
    float logit = acc + gb[e];
    float mx = logit;
    mx = fmaxf(mx, __shfl_xor(mx, 1));
    mx = fmaxf(mx, __shfl_xor(mx, 2));
    mx = fmaxf(mx, __shfl_xor(mx, 4));
    float ex = expf(logit - mx);
    float sum = ex;
    sum += __shfl_xor(sum, 1);
    sum += __shfl_xor(sum, 2);
    sum += __shfl_xor(sum, 4);
    if (lane < 8) gate[b * NEXP + e] = ex / sum;
}

// ---------------------------------------------------------------------------
// Generic tiled fp32 matmul: C = A1*B1^T [+ sgn*A2*B2^T]  (B stored [N][K] row-major)
// Epilogue: RELU -> C = relu(acc+bias) ; GATED -> C += g*(acc+bias) ; else C = acc(+bias)
// Optional kptr = {start,end}: restrict K-range (columns of A and B offset by start).
// Tile 64x64, BK=16, 256 threads, 4x4 micro-tile.
// ---------------------------------------------------------------------------
template <bool DUAL, bool RELU, bool GATED>
__global__ void mm_kernel(const float* __restrict__ A1, const float* __restrict__ A2, int lda,
                          const float* __restrict__ B1, const float* __restrict__ B2, int ldb,
                          float* __restrict__ C, int ldc,
                          int M, int N, int K, const int* __restrict__ kptr,
                          float sgn, const float* __restrict__ bias,
                          const float* __restrict__ gate, int gateStride, int rowsPerB) {
    __shared__ float As1[64][17], Bs1[64][17];
    __shared__ float As2[DUAL ? 64 : 1][17], Bs2[DUAL ? 64 : 1][17];

    int kS = 0, kE = K;
    if (kptr) { kS = kptr[0]; kE = kptr[1]; }
    int Kn = kE - kS;
    const float* a1 = A1 + kS;
    const float* b1 = B1 + kS;
    const float* a2 = DUAL ? (A2 + kS) : nullptr;
    const float* b2 = DUAL ? (B2 + kS) : nullptr;

    int row0 = blockIdx.y * 64;
    int col0 = blockIdx.x * 64;
    int tid = threadIdx.x;
    int tr = tid >> 4, tc = tid & 15;

    float acc[4][4] = {};

    for (int k0 = 0; k0 < Kn; k0 += 16) {
        for (int l = 0; l < 4; l++) {
            int idx = tid + l * 256;
            int r = idx >> 4, kk = idx & 15;
            int gk = k0 + kk;
            bool okk = (gk < Kn);
            int gr = row0 + r;
            bool oka = okk && (gr < M);
            As1[r][kk] = oka ? a1[(long)gr * lda + gk] : 0.0f;
            if (DUAL) As2[r][kk] = oka ? a2[(long)gr * lda + gk] : 0.0f;
            int gn = col0 + r;
            bool okb = okk && (gn < N);
            Bs1[r][kk] = okb ? b1[(long)gn * ldb + gk] : 0.0f;
            if (DUAL) Bs2[r][kk] = okb ? b2[(long)gn * ldb + gk] : 0.0f;
        }
        __syncthreads();
#pragma unroll
        for (int kk = 0; kk < 16; kk++) {
            float av1[4], bv1[4];
#pragma unroll
            for (int i = 0; i < 4; i++) av1[i] = As1[tr * 4 + i][kk];
#pragma unroll
            for (int j = 0; j < 4; j++) bv1[j] = Bs1[tc * 4 + j][kk];
#pragma unroll
            for (int i = 0; i < 4; i++)
#pragma unroll
                for (int j = 0; j < 4; j++) acc[i][j] += av1[i] * bv1[j];
            if (DUAL) {
                float av2[4], bv2[4];
#pragma unroll
                for (int i = 0; i < 4; i++) av2[i] = As2[tr * 4 + i][kk];
#pragma unroll
                for (int j = 0; j < 4; j++) bv2[j] = Bs2[tc * 4 + j][kk] * sgn;
#pragma unroll
                for (int i = 0; i < 4; i++)
#pragma unroll
                    for (int j = 0; j < 4; j++) acc[i][j] += av2[i] * bv2[j];
            }
        }
        __syncthreads();
    }

#pragma unroll
    for (int i = 0; i < 4; i++) {
        int r = row0 + tr * 4 + i;
        if (r >= M) continue;
        float g = 1.0f;
        if (GATED) g = gate[(r / rowsPerB) * gateStride];
#pragma unroll
        for (int j = 0; j < 4; j++) {
            int n = col0 + tc * 4 + j;
            if (n >= N) continue;
            float v = acc[i][j];
            if (bias) v += bias[n];
            if (RELU) v = fmaxf(v, 0.0f);
            long o = (long)r * ldc + n;
            if (GATED) C[o] += g * v;
            else       C[o] = v;
        }
    }
}

// ---------------------------------------------------------------------------
extern "C" void kernel_launch(void* const* d_in, const int* in_sizes, int n_in,
                              void* d_out, int out_size, void* d_ws, size_t ws_size,
                              hipStream_t stream) {
    const float* X   = (const float*)d_in[0];
    const float* bp  = (const float*)d_in[1];
    const float* W1r = (const float*)d_in[2];
    const float* W1i = (const float*)d_in[3];
    const float* b1r = (const float*)d_in[4];
    const float* b1i = (const float*)d_in[5];
    const float* W2r = (const float*)d_in[6];
    const float* W2i = (const float*)d_in[7];
    const float* b2r = (const float*)d_in[8];
    const float* b2i = (const float*)d_in[9];
    const float* gW  = (const float*)d_in[10];
    const float* gb  = (const float*)d_in[11];
    float* out = (float*)d_out;

    float* ws = (float*)d_ws;
    size_t off = 0;
    float* Ffwd   = ws + off; off += (size_t)HDIM * LENN;
    float* Finv_c = ws + off; off += (size_t)LENN * FBINS;
    float* Finv_s = ws + off; off += (size_t)LENN * FBINS;
    float* XrXi   = ws + off; off += (size_t)MROWS * HDIM;
    float* hr     = ws + off; off += (size_t)MROWS * HDIM;
    float* hi     = ws + off; off += (size_t)MROWS * HDIM;
    float* comb_r = ws + off; off += (size_t)MROWS * FBINS;
    float* comb_i = ws + off; off += (size_t)MROWS * FBINS;   // contiguous after comb_r
    float* mag    = ws + off; off += (size_t)BATCH * FBINS;
    float* gate   = ws + off; off += (size_t)BATCH * NEXP;
    int*   se     = (int*)(ws + off); off += 16;

    long total_tab = (long)HDIM * LENN + 2L * LENN * FBINS;
    gen_tables<<<dim3((unsigned)((total_tab + 255) / 256)), 256, 0, stream>>>(Ffwd, Finv_c, Finv_s);
    prep_kernel<<<1, 64, 0, stream>>>(bp, se);

    dim3 blk(256);
    // Forward DFT: XrXi[4096][1026] = X[4096][1024] * Ffwd^T
    mm_kernel<false, false, false><<<dim3((HDIM + 63) / 64, MROWS / 64), blk, 0, stream>>>(
        X, nullptr, LENN, Ffwd, nullptr, LENN, XrXi, HDIM,
        MROWS, HDIM, LENN, nullptr, 1.0f, nullptr, nullptr, 0, 0);

    mag_kernel<<<dim3((FBINS + 255) / 256, BATCH), 256, 0, stream>>>(XrXi, mag);
    gate_kernel<<<BATCH, 64, 0, stream>>>(mag, gW, gb, gate);

    hipMemsetAsync(comb_r, 0, 2L * MROWS * FBINS * sizeof(float), stream);

    for (int e = 0; e < NEXP; e++) {
        const float* w1r = W1r + (size_t)e * HDIM * FBINS;
        const float* w1i = W1i + (size_t)e * HDIM * FBINS;
        const float* w2r = W2r + (size_t)e * FBINS * HDIM;
        const float* w2i = W2i + (size_t)e * FBINS * HDIM;
        // hr = relu(Xr*W1r^T - Xi*W1i^T + b1r)   (K-range from se[2e..2e+1])
        mm_kernel<true, true, false><<<dim3((HDIM + 63) / 64, MROWS / 64), blk, 0, stream>>>(
            XrXi, XrXi + FBINS, HDIM, w1r, w1i, FBINS, hr, HDIM,
            MROWS, HDIM, 0, se + 2 * e, -1.0f, b1r + e * HDIM, nullptr, 0, 0);
        // hi = relu(Xr*W1i^T + Xi*W1r^T + b1i)
        mm_kernel<true, true, false><<<dim3((HDIM + 63) / 64, MROWS / 64), blk, 0, stream>>>(
            XrXi, XrXi + FBINS, HDIM, w1i, w1r, FBINS, hi, HDIM,
            MROWS, HDIM, 0, se + 2 * e, 1.0f, b1i + e * HDIM, nullptr, 0, 0);
        // comb_r += g * (hr*W2r^T - hi*W2i^T + b2r)
        mm_kernel<true, false, true><<<dim3((FBINS + 63) / 64, MROWS / 64), blk, 0, stream>>>(
            hr, hi, HDIM, w2r, w2i, HDIM, comb_r, FBINS,
            MROWS, FBINS, HDIM, nullptr, -1.0f, b2r + e * FBINS, gate + e, NEXP, CHAN);
        // comb_i += g * (hr*W2i^T + hi*W2r^T + b2i)
        mm_kernel<true, false, true><<<dim3((FBINS + 63) / 64, MROWS / 64), blk, 0, stream>>>(
            hr, hi, HDIM, w2i, w2r, HDIM, comb_i, FBINS,
            MROWS, FBINS, HDIM, nullptr, 1.0f, b2i + e * FBINS, gate + e, NEXP, CHAN);
    }

    // Inverse DFT: out[4096][1024] = comb_r*Finv_c^T + comb_i*Finv_s^T
    mm_kernel<true, false, false><<<dim3(LENN / 64, MROWS / 64), blk, 0, stream>>>(
        comb_r, comb_i, FBINS, Finv_c, Finv_s, FBINS, out, LENN,
        MROWS, LENN, FBINS, nullptr, 1.0f, nullptr, nullptr, 0, 0);
}

// Round 2
// 863.161 us; speedup vs baseline: 9.7910x; 9.7910x over previous
//
#include <hip/hip_runtime.h>
#include <hip/hip_bf16.h>
#include <math.h>

typedef __hip_bfloat16 bf16;
typedef __attribute__((ext_vector_type(8))) short short8;
typedef __attribute__((ext_vector_type(4))) float f32x4;

#define FB 513
#define HD 1026
#define NN 1024
#define MR 4096      // 32*128 rows
#define NE 8
#define BATCH 32

#define XINT_LD 1056   // 2*FB=1026 padded to 33*32
#define H_LD    2080   // 2*HD=2052 padded to 65*32
#define B1_ROWS 2176   // 17*128 (N=2052)
#define B2_ROWS 1152   // 9*128  (N=1026)
#define FF_ROWS 1152   // 9*128  (N=1026)

__device__ __forceinline__ void gload16(const void* g, void* l) {
    __builtin_amdgcn_global_load_lds((const __attribute__((address_space(1))) void*)g,
                                     (__attribute__((address_space(3))) void*)l, 16, 0, 0);
}
__device__ __forceinline__ bf16 f2b(float v) { return __float2bfloat16(v); }

// ---------------------------------------------------------------------------
// prep: sigmoid, sort, idx -> se[2e]={start,end}
// ---------------------------------------------------------------------------
__global__ void prep_kernel(const float* __restrict__ bp, int* __restrict__ se) {
    if (threadIdx.x == 0 && blockIdx.x == 0) {
        float b[9];
        b[0] = 0.0f; b[8] = 1.0f;
        for (int i = 0; i < 7; i++) b[i + 1] = 1.0f / (1.0f + expf(-bp[i]));
        for (int i = 1; i < 9; i++) { float v = b[i]; int j = i - 1;
            while (j >= 0 && b[j] > v) { b[j + 1] = b[j]; j--; } b[j + 1] = v; }
        int idx[9];
        for (int i = 0; i < 9; i++) idx[i] = (int)(b[i] * (float)(FB - 1));
        for (int e = 0; e < NE; e++) {
            se[2 * e] = idx[e];
            se[2 * e + 1] = (e < NE - 1) ? idx[e + 1] : FB;
        }
    }
}

// ---------------------------------------------------------------------------
// X fp32 -> bf16 (4/thread)
// ---------------------------------------------------------------------------
__global__ void convert_X(const float* __restrict__ X, bf16* __restrict__ Xb) {
    long i = ((long)blockIdx.x * 256 + threadIdx.x) * 4;
    if (i >= (long)MR * NN) return;
    float4 v = *(const float4*)(X + i);
    bf16* o = Xb + i;
    o[0] = f2b(v.x); o[1] = f2b(v.y); o[2] = f2b(v.z); o[3] = f2b(v.w);
}

// ---------------------------------------------------------------------------
// Tables (bf16): Ffwd[1152][1024] rows 2f=cos, 2f+1=-sin ; Finv[1024][1056]
// cols 2f=c_f*cos/N, 2f+1=-c_f*sin/N
// ---------------------------------------------------------------------------
__global__ void gen_tables(bf16* __restrict__ Ffwd, bf16* __restrict__ Finv) {
    long i = (long)blockIdx.x * 256 + threadIdx.x;
    const long nF = (long)FF_ROWS * NN, nI = (long)NN * XINT_LD;
    const float TWO_PI = 6.283185307179586f;
    if (i < nF) {
        int n = (int)(i >> 10), t = (int)(i & (NN - 1));
        float v = 0.0f;
        if (n < 2 * FB) {
            int f = n >> 1, k = (f * t) & (NN - 1);
            float s, c; sincosf(TWO_PI * (float)k / (float)NN, &s, &c);
            v = (n & 1) ? -s : c;
        }
        Ffwd[i] = f2b(v);
    } else if (i < nF + nI) {
        long j = i - nF;
        int t = (int)(j / XINT_LD), k = (int)(j % XINT_LD);
        float v = 0.0f;
        if (k < 2 * FB) {
            int f = k >> 1, kk = (f * t) & (NN - 1);
            float s, c; sincosf(TWO_PI * (float)kk / (float)NN, &s, &c);
            float cf = (f == 0 || f == FB - 1) ? 1.0f : 2.0f;
            float sc = cf * (1.0f / (float)NN);
            v = (k & 1) ? -s * sc : c * sc;
        }
        Finv[j] = f2b(v);
    }
}

// ---------------------------------------------------------------------------
// Pack B1[e][2176][1056]: n<1026 -> hr row h=n: (2f)=W1r[h][f], (2f+1)=-W1i[h][f]
//                         n in [1026,2052) -> hi row h=n-1026: (2f)=W1i, (2f+1)=W1r
// zero outside expert bin range [s,e) and in all pads.
// ---------------------------------------------------------------------------
__global__ void pack_B1(const float* __restrict__ W1r, const float* __restrict__ W1i,
                        const int* __restrict__ se, bf16* __restrict__ B1) {
    long i = (long)blockIdx.x * 256 + threadIdx.x;
    const long total = (long)NE * B1_ROWS * XINT_LD;
    if (i >= total) return;
    int k = (int)(i % XINT_LD);
    long t = i / XINT_LD;
    int n = (int)(t % B1_ROWS);
    int e = (int)(t / B1_ROWS);
    float v = 0.0f;
    int f = k >> 1;
    if (n < 2 * HD && k < 2 * FB && f >= se[2 * e] && f < se[2 * e + 1]) {
        int hi_part = (n >= HD);
        int h = hi_part ? n - HD : n;
        long wi = ((long)e * HD + h) * FB + f;
        float wr = W1r[wi], wim = W1i[wi];
        v = (k & 1) ? (hi_part ? wr : -wim) : (hi_part ? wim : wr);
    }
    B1[i] = f2b(v);
}

// ---------------------------------------------------------------------------
// Pack B2[e][1152][2080]: n=2f (yr): k<1026 -> W2r[f][k], k in [1026,2052) -> -W2i[f][k-1026]
//                         n=2f+1 (yi): k<1026 -> W2i[f][k], else W2r[f][k-1026]
// ---------------------------------------------------------------------------
__global__ void pack_B2(const float* __restrict__ W2r, const float* __restrict__ W2i,
                        bf16* __restrict__ B2) {
    long i = (long)blockIdx.x * 256 + threadIdx.x;
    const long total = (long)NE * B2_ROWS * H_LD;
    if (i >= total) return;
    int k = (int)(i % H_LD);
    long t = i / H_LD;
    int n = (int)(t % B2_ROWS);
    int e = (int)(t / B2_ROWS);
    float v = 0.0f;
    if (n < 2 * FB && k < 2 * HD) {
        int f = n >> 1, yi = n & 1;
        int hi_part = (k >= HD);
        int h = hi_part ? k - HD : k;
        long wi = ((long)e * FB + f) * HD + h;
        float wr = W2r[wi], wim = W2i[wi];
        v = yi ? (hi_part ? wr : wim) : (hi_part ? -wim : wr);
    }
    B2[i] = f2b(v);
}

// ---------------------------------------------------------------------------
// mag[b][f] = mean_c |Xf|, reading interleaved bf16 Xint
// ---------------------------------------------------------------------------
__global__ void mag_kernel(const bf16* __restrict__ Xint, float* __restrict__ mag) {
    int f = blockIdx.x * 256 + threadIdx.x;
    int b = blockIdx.y;
    if (f >= FB) return;
    const bf16* base = Xint + (long)b * 128 * XINT_LD + 2 * f;
    float acc = 0.0f;
    for (int c = 0; c < 128; c++) {
        float xr = __bfloat162float(base[(long)c * XINT_LD]);
        float xi = __bfloat162float(base[(long)c * XINT_LD + 1]);
        acc += sqrtf(xr * xr + xi * xi);
    }
    mag[b * FB + f] = acc * (1.0f / 128.0f);
}

// ---------------------------------------------------------------------------
// gate[b][e] = softmax_e(mag[b] . gW[e] + gb[e]); one wave per b
// ---------------------------------------------------------------------------
__global__ void gate_kernel(const float* __restrict__ mag, const float* __restrict__ gW,
                            const float* __restrict__ gb, float* __restrict__ gate) {
    int b = blockIdx.x, lane = threadIdx.x;
    int e = lane & 7, j = lane >> 3;
    float acc = 0.0f;
    for (int f = j; f < FB; f += 8) acc += mag[b * FB + f] * gW[e * FB + f];
    acc += __shfl_xor(acc, 8); acc += __shfl_xor(acc, 16); acc += __shfl_xor(acc, 32);
    float logit = acc + gb[e];
    float mx = logit;
    mx = fmaxf(mx, __shfl_xor(mx, 1)); mx = fmaxf(mx, __shfl_xor(mx, 2)); mx = fmaxf(mx, __shfl_xor(mx, 4));
    float ex = expf(logit - mx);
    float sum = ex;
    sum += __shfl_xor(sum, 1); sum += __shfl_xor(sum, 2); sum += __shfl_xor(sum, 4);
    if (lane < 8) gate[b * NE + e] = ex / sum;
}

// ---------------------------------------------------------------------------
// comb fp32 [4096][1026] -> bf16 [4096][1056] with zero pad (2 cols/thread)
// ---------------------------------------------------------------------------
__global__ void convert_comb(const float* __restrict__ comb, bf16* __restrict__ cb) {
    long i = (long)blockIdx.x * 256 + threadIdx.x;
    const long total = (long)MR * (XINT_LD / 2);
    if (i >= total) return;
    int c2 = (int)(i % (XINT_LD / 2));
    long r = i / (XINT_LD / 2);
    int c = c2 * 2;
    bf16* o = cb + r * XINT_LD + c;
    if (c < 2 * FB) {
        o[0] = f2b(comb[r * (2 * FB) + c]);
        o[1] = f2b(comb[r * (2 * FB) + c + 1]);
    } else { o[0] = f2b(0.0f); o[1] = f2b(0.0f); }
}

// ---------------------------------------------------------------------------
// MFMA GEMM: C[M=4096][N] = A[4096][K]*B[N][K]^T  (all bf16, fp32 acc)
// 128x128 tile, BK=32, 4 waves (2x2), 4x4 mfma_f32_16x16x32_bf16 per wave.
// EPI: 0=store bf16, 1=relu(acc+bias[L1]) bf16, 2=comb += gate*(acc+bias[L2]) f32, 3=store f32
// se2: optional {startBin,endBin} -> K-range [2s & ~31, roundup32(2e))
// ---------------------------------------------------------------------------
template <int EPI>
__global__ void gemm_mfma(const bf16* __restrict__ A, int lda,
                          const bf16* __restrict__ B, int ldb,
                          void* __restrict__ Cv, int ldc, int N, int K,
                          const int* __restrict__ se2,
                          const float* __restrict__ biasR, const float* __restrict__ biasI,
                          const float* __restrict__ gate8) {
    __shared__ bf16 As[128 * 32];
    __shared__ bf16 Bs[128 * 32];
    int tid = threadIdx.x;
    int row0 = blockIdx.y * 128, col0 = blockIdx.x * 128;

    int kS = 0, kE = K;
    if (se2) { int s = se2[0], e = se2[1]; kS = (2 * s) & ~31; kE = (2 * e + 31) & ~31; }

    f32x4 acc[4][4] = {};

    int lane = tid & 63, wid = tid >> 6;
    int wrB = (wid >> 1) << 6, wcB = (wid & 1) << 6;
    int lr = lane & 15, lk = (lane >> 4) << 3;

    int r_a = tid >> 2, c_a = (tid & 3) << 3;          // load 0: elem (tid)*8
    int r_b = (tid + 256) >> 2, c_b = ((tid + 256) & 3) << 3;

    for (int kt = kS; kt < kE; kt += 32) {
        gload16(A + (size_t)(row0 + r_a) * lda + kt + c_a, &As[(size_t)tid * 8]);
        gload16(A + (size_t)(row0 + r_b) * lda + kt + c_b, &As[((size_t)tid + 256) * 8]);
        gload16(B + (size_t)(col0 + r_a) * ldb + kt + c_a, &Bs[(size_t)tid * 8]);
        gload16(B + (size_t)(col0 + r_b) * ldb + kt + c_b, &Bs[((size_t)tid + 256) * 8]);
        __syncthreads();
        short8 av[4], bv[4];
#pragma unroll
        for (int m = 0; m < 4; m++)
            av[m] = *(const short8*)&As[(wrB + m * 16 + lr) * 32 + lk];
#pragma unroll
        for (int n = 0; n < 4; n++)
            bv[n] = *(const short8*)&Bs[(wcB + n * 16 + lr) * 32 + lk];
#pragma unroll
        for (int m = 0; m < 4; m++)
#pragma unroll
            for (int n = 0; n < 4; n++)
                acc[m][n] = __builtin_amdgcn_mfma_f32_16x16x32_bf16(av[m], bv[n], acc[m][n], 0, 0, 0);
        __syncthreads();
    }

    int r0 = row0 + wrB + ((lane >> 4) << 2);
    int c0i = col0 + wcB + (lane & 15);
#pragma unroll
    for (int m = 0; m < 4; m++)
#pragma unroll
        for (int n = 0; n < 4; n++) {
            int c = c0i + n * 16;
            if (c >= N) continue;
#pragma unroll
            for (int j = 0; j < 4; j++) {
                int r = r0 + m * 16 + j;
                float v = acc[m][n][j];
                if (EPI == 1) { v += (c < HD) ? biasR[c] : biasI[c - HD]; v = fmaxf(v, 0.0f); }
                if (EPI == 2) v += (c & 1) ? biasI[c >> 1] : biasR[c >> 1];
                if (EPI == 0 || EPI == 1) ((bf16*)Cv)[(size_t)r * ldc + c] = f2b(v);
                else if (EPI == 3) ((float*)Cv)[(size_t)r * ldc + c] = v;
                else {
                    float g = gate8[(r >> 7) * NE];
                    ((float*)Cv)[(size_t)r * ldc + c] += g * v;
                }
            }
        }
}

// ---------------------------------------------------------------------------
extern "C" void kernel_launch(void* const* d_in, const int* in_sizes, int n_in,
                              void* d_out, int out_size, void* d_ws, size_t ws_size,
                              hipStream_t stream) {
    const float* X   = (const float*)d_in[0];
    const float* bp  = (const float*)d_in[1];
    const float* W1r = (const float*)d_in[2];
    const float* W1i = (const float*)d_in[3];
    const float* b1r = (const float*)d_in[4];
    const float* b1i = (const float*)d_in[5];
    const float* W2r = (const float*)d_in[6];
    const float* W2i = (const float*)d_in[7];
    const float* b2r = (const float*)d_in[8];
    const float* b2i = (const float*)d_in[9];
    const float* gW  = (const float*)d_in[10];
    const float* gb  = (const float*)d_in[11];
    float* out = (float*)d_out;

    // ---- workspace layout (fp32 region, then bf16 region; all 16B aligned)
    char* wsb = (char*)d_ws;
    float* comb = (float*)wsb;                         // 4096*1026 f32
    float* mag  = comb + (size_t)MR * 2 * FB;          // 32*513
    float* gate = mag + (size_t)BATCH * FB;            // pad to keep alignment below
    int*   se   = (int*)(gate + 256);                  // 16 ints
    bf16*  Xb   = (bf16*)(se + 16);                    // 4096*1024
    bf16*  Xint = Xb + (size_t)MR * NN;                // 4096*1056
    bf16*  H    = Xint + (size_t)MR * XINT_LD;         // 4096*2080
    bf16*  Ffwd = H + (size_t)MR * H_LD;               // 1152*1024
    bf16*  Finv = Ffwd + (size_t)FF_ROWS * NN;         // 1024*1056
    bf16*  B1   = Finv + (size_t)NN * XINT_LD;         // 8*2176*1056
    bf16*  B2   = B1 + (size_t)NE * B1_ROWS * XINT_LD; // 8*1152*2080
    bf16*  combb= B2 + (size_t)NE * B2_ROWS * H_LD;    // 4096*1056

    // ---- prep + tables + packing
    prep_kernel<<<1, 64, 0, stream>>>(bp, se);
    convert_X<<<(unsigned)(((size_t)MR * NN / 4 + 255) / 256), 256, 0, stream>>>(X, Xb);
    {
        long tot = (long)FF_ROWS * NN + (long)NN * XINT_LD;
        gen_tables<<<(unsigned)((tot + 255) / 256), 256, 0, stream>>>(Ffwd, Finv);
    }
    {
        long tot = (long)NE * B1_ROWS * XINT_LD;
        pack_B1<<<(unsigned)((tot + 255) / 256), 256, 0, stream>>>(W1r, W1i, se, B1);
    }
    {
        long tot = (long)NE * B2_ROWS * H_LD;
        pack_B2<<<(unsigned)((tot + 255) / 256), 256, 0, stream>>>(W2r, W2i, B2);
    }

    // ---- forward DFT: Xint[4096][1026(i)] = Xb * Ffwd^T
    gemm_mfma<0><<<dim3(9, 32), 256, 0, stream>>>(Xb, NN, Ffwd, NN, Xint, XINT_LD,
                                                  2 * FB, NN, nullptr, nullptr, nullptr, nullptr);

    // ---- gate
    mag_kernel<<<dim3(3, BATCH), 256, 0, stream>>>(Xint, mag);
    gate_kernel<<<BATCH, 64, 0, stream>>>(mag, gW, gb, gate);

    // ---- expert loop
    hipMemsetAsync(comb, 0, (size_t)MR * 2 * FB * sizeof(float), stream);
    for (int e = 0; e < NE; e++) {
        // L1: H[4096][2052] = relu(Xint * B1_e^T + bias), K-range from se
        gemm_mfma<1><<<dim3(17, 32), 256, 0, stream>>>(
            Xint, XINT_LD, B1 + (size_t)e * B1_ROWS * XINT_LD, XINT_LD, H, H_LD,
            2 * HD, 0, se + 2 * e, b1r + (size_t)e * HD, b1i + (size_t)e * HD, nullptr);
        // L2: comb += g_e * (H * B2_e^T + bias)
        gemm_mfma<2><<<dim3(9, 32), 256, 0, stream>>>(
            H, H_LD, B2 + (size_t)e * B2_ROWS * H_LD, H_LD, comb, 2 * FB,
            2 * FB, H_LD, nullptr, b2r + (size_t)e * FB, b2i + (size_t)e * FB, gate + e);
    }

    // ---- comb -> bf16, then inverse DFT: out = combb * Finv^T
    convert_comb<<<(unsigned)(((size_t)MR * (XINT_LD / 2) + 255) / 256), 256, 0, stream>>>(comb, combb);
    gemm_mfma<3><<<dim3(8, 32), 256, 0, stream>>>(combb, XINT_LD, Finv, XINT_LD, out, NN,
                                                  NN, XINT_LD, nullptr, nullptr, nullptr, nullptr);
}

// Round 3
// 658.982 us; speedup vs baseline: 12.8246x; 1.3098x over previous
//
#include <hip/hip_runtime.h>
#include <hip/hip_bf16.h>
#include <math.h>

typedef __hip_bfloat16 bf16;
typedef __attribute__((ext_vector_type(8))) short short8;
typedef __attribute__((ext_vector_type(4))) float f32x4;

#define FB 513
#define HD 1026
#define NN 1024
#define MR 4096      // 32*128 rows
#define NE 8
#define BATCH 32

#define XINT_LD 1056   // 2*FB=1026 padded to 33*32
#define HP_LD   2080   // 2*HD=2052 padded (per-expert window in H')
#define B1_ROWS 2176   // 17*128 (N=2052)
#define B2_ROWS 1152   // 9*128  (N=1026)
#define FF_ROWS 1152   // 9*128
#define KCAT    16640  // 8*2080

__device__ __forceinline__ void gload16(const void* g, void* l) {
    __builtin_amdgcn_global_load_lds((const __attribute__((address_space(1))) void*)g,
                                     (__attribute__((address_space(3))) void*)l, 16, 0, 0);
}
__device__ __forceinline__ bf16 f2b(float v) { return __float2bfloat16(v); }

// ---------------------------------------------------------------------------
__global__ void prep_kernel(const float* __restrict__ bp, int* __restrict__ se) {
    if (threadIdx.x == 0 && blockIdx.x == 0) {
        float b[9];
        b[0] = 0.0f; b[8] = 1.0f;
        for (int i = 0; i < 7; i++) b[i + 1] = 1.0f / (1.0f + expf(-bp[i]));
        for (int i = 1; i < 9; i++) { float v = b[i]; int j = i - 1;
            while (j >= 0 && b[j] > v) { b[j + 1] = b[j]; j--; } b[j + 1] = v; }
        int idx[9];
        for (int i = 0; i < 9; i++) idx[i] = (int)(b[i] * (float)(FB - 1));
        for (int e = 0; e < NE; e++) {
            se[2 * e] = idx[e];
            se[2 * e + 1] = (e < NE - 1) ? idx[e + 1] : FB;
        }
    }
}

// ---------------------------------------------------------------------------
__global__ void convert_X(const float* __restrict__ X, bf16* __restrict__ Xb) {
    long i = ((long)blockIdx.x * 256 + threadIdx.x) * 4;
    if (i >= (long)MR * NN) return;
    float4 v = *(const float4*)(X + i);
    bf16* o = Xb + i;
    o[0] = f2b(v.x); o[1] = f2b(v.y); o[2] = f2b(v.z); o[3] = f2b(v.w);
}

// ---------------------------------------------------------------------------
// Ffwd[1152][1024] rows 2f=cos, 2f+1=-sin ; Finv[1024][1056] cols 2f=c_f*cos/N, 2f+1=-c_f*sin/N
// ---------------------------------------------------------------------------
__global__ void gen_tables(bf16* __restrict__ Ffwd, bf16* __restrict__ Finv) {
    long i = (long)blockIdx.x * 256 + threadIdx.x;
    const long nF = (long)FF_ROWS * NN, nI = (long)NN * XINT_LD;
    const float TWO_PI = 6.283185307179586f;
    if (i < nF) {
        int n = (int)(i >> 10), t = (int)(i & (NN - 1));
        float v = 0.0f;
        if (n < 2 * FB) {
            int f = n >> 1, k = (f * t) & (NN - 1);
            float s, c; sincosf(TWO_PI * (float)k / (float)NN, &s, &c);
            v = (n & 1) ? -s : c;
        }
        Ffwd[i] = f2b(v);
    } else if (i < nF + nI) {
        long j = i - nF;
        int t = (int)(j / XINT_LD), k = (int)(j % XINT_LD);
        float v = 0.0f;
        if (k < 2 * FB) {
            int f = k >> 1, kk = (f * t) & (NN - 1);
            float s, c; sincosf(TWO_PI * (float)kk / (float)NN, &s, &c);
            float cf = (f == 0 || f == FB - 1) ? 1.0f : 2.0f;
            float sc = cf * (1.0f / (float)NN);
            v = (k & 1) ? -s * sc : c * sc;
        }
        Finv[j] = f2b(v);
    }
}

// ---------------------------------------------------------------------------
// B1[e][2176][1056]: n<1026 -> (2f)=W1r[n][f], (2f+1)=-W1i[n][f];
//                    n in [1026,2052) h=n-1026 -> (2f)=W1i, (2f+1)=W1r ; masked to bin range
// ---------------------------------------------------------------------------
__global__ void pack_B1(const float* __restrict__ W1r, const float* __restrict__ W1i,
                        const int* __restrict__ se, bf16* __restrict__ B1) {
    long i = (long)blockIdx.x * 256 + threadIdx.x;
    const long total = (long)NE * B1_ROWS * XINT_LD;
    if (i >= total) return;
    int k = (int)(i % XINT_LD);
    long t = i / XINT_LD;
    int n = (int)(t % B1_ROWS);
    int e = (int)(t / B1_ROWS);
    float v = 0.0f;
    int f = k >> 1;
    if (n < 2 * HD && k < 2 * FB && f >= se[2 * e] && f < se[2 * e + 1]) {
        int hi_part = (n >= HD);
        int h = hi_part ? n - HD : n;
        long wi = ((long)e * HD + h) * FB + f;
        float wr = W1r[wi], wim = W1i[wi];
        v = (k & 1) ? (hi_part ? wr : -wim) : (hi_part ? wim : wr);
    }
    B1[i] = f2b(v);
}

// ---------------------------------------------------------------------------
// B2cat[1152][16640]: col = e*2080 + k ; n=2f (yr): k<1026 -> W2r[f][k], [1026,2052) -> -W2i
//                                        n=2f+1 (yi): k<1026 -> W2i, else W2r
// ---------------------------------------------------------------------------
__global__ void pack_B2(const float* __restrict__ W2r, const float* __restrict__ W2i,
                        bf16* __restrict__ B2) {
    long i = (long)blockIdx.x * 256 + threadIdx.x;
    const long total = (long)B2_ROWS * KCAT;
    if (i >= total) return;
    int col = (int)(i % KCAT);
    int n = (int)(i / KCAT);
    int e = col / HP_LD, k = col % HP_LD;
    float v = 0.0f;
    if (n < 2 * FB && k < 2 * HD) {
        int f = n >> 1, yi = n & 1;
        int hi_part = (k >= HD);
        int h = hi_part ? k - HD : k;
        long wi = ((long)e * FB + f) * HD + h;
        float wr = W2r[wi], wim = W2i[wi];
        v = yi ? (hi_part ? wr : wim) : (hi_part ? -wim : wr);
    }
    B2[i] = f2b(v);
}

// ---------------------------------------------------------------------------
// mag[b][f] = mean_c |Xf|; one block per b, coalesced u32 loads of (2f,2f+1)
// ---------------------------------------------------------------------------
__global__ void mag_kernel(const bf16* __restrict__ Xint, float* __restrict__ mag) {
    int b = blockIdx.x, t = threadIdx.x;
    float acc[3] = {0.0f, 0.0f, 0.0f};
    const bf16* base = Xint + (size_t)b * 128 * XINT_LD;
    for (int c = 0; c < 128; c++) {
        const bf16* row = base + (size_t)c * XINT_LD;
#pragma unroll
        for (int kk = 0; kk < 3; kk++) {
            int f = t + 256 * kk;
            if (f < FB) {
                float xr = __bfloat162float(row[2 * f]);
                float xi = __bfloat162float(row[2 * f + 1]);
                acc[kk] += sqrtf(xr * xr + xi * xi);
            }
        }
    }
#pragma unroll
    for (int kk = 0; kk < 3; kk++) {
        int f = t + 256 * kk;
        if (f < FB) mag[b * FB + f] = acc[kk] * (1.0f / 128.0f);
    }
}

// ---------------------------------------------------------------------------
__global__ void gate_kernel(const float* __restrict__ mag, const float* __restrict__ gW,
                            const float* __restrict__ gb, float* __restrict__ gate) {
    int b = blockIdx.x, lane = threadIdx.x;
    int e = lane & 7, j = lane >> 3;
    float acc = 0.0f;
    for (int f = j; f < FB; f += 8) acc += mag[b * FB + f] * gW[e * FB + f];
    acc += __shfl_xor(acc, 8); acc += __shfl_xor(acc, 16); acc += __shfl_xor(acc, 32);
    float logit = acc + gb[e];
    float mx = logit;
    mx = fmaxf(mx, __shfl_xor(mx, 1)); mx = fmaxf(mx, __shfl_xor(mx, 2)); mx = fmaxf(mx, __shfl_xor(mx, 4));
    float ex = expf(logit - mx);
    float sum = ex;
    sum += __shfl_xor(sum, 1); sum += __shfl_xor(sum, 2); sum += __shfl_xor(sum, 4);
    if (lane < 8) gate[b * NE + e] = ex / sum;
}

// ---------------------------------------------------------------------------
// biasC[b][c] = sum_e gate[b][e] * (c&1 ? b2i : b2r)[e][c>>1]   (c<1026, else 0)
// ---------------------------------------------------------------------------
__global__ void biasC_kernel(const float* __restrict__ gate, const float* __restrict__ b2r,
                             const float* __restrict__ b2i, float* __restrict__ biasC) {
    int i = blockIdx.x * 256 + threadIdx.x;
    if (i >= BATCH * XINT_LD) return;
    int b = i / XINT_LD, c = i % XINT_LD;
    float v = 0.0f;
    if (c < 2 * FB) {
        int f = c >> 1;
        const float* bb = (c & 1) ? b2i : b2r;
#pragma unroll
        for (int e = 0; e < NE; e++) v += gate[b * NE + e] * bb[e * FB + f];
    }
    biasC[i] = v;
}

// ---------------------------------------------------------------------------
// combb[r][c] = bf16( sum_z partial[z][r][c] + biasC[b][c] )  (c<1026 else 0)
// ---------------------------------------------------------------------------
__global__ void reduce_comb(const float* __restrict__ partial, int splitk,
                            const float* __restrict__ biasC, bf16* __restrict__ combb) {
    long i = (long)blockIdx.x * 256 + threadIdx.x;
    if (i >= (long)MR * XINT_LD) return;
    int c = (int)(i % XINT_LD);
    long r = i / XINT_LD;
    float v = 0.0f;
    if (c < 2 * FB) {
        v = partial[i];
        if (splitk == 2) v += partial[(size_t)MR * XINT_LD + i];
        v += biasC[(int)(r >> 7) * XINT_LD + c];
    }
    combb[i] = f2b(v);
}

// ---------------------------------------------------------------------------
// MFMA GEMM: C = A[4096][K]*B[N][K]^T (bf16 in, fp32 acc). 128x128 tile, BK=32,
// 4 waves, 4x4 mfma_f32_16x16x32_bf16.
// EPI 0: store bf16 (DFT)
// EPI 1: per-z expert: K-range from se2[2z..], v=relu(acc+bias)*gate -> bf16 (L1)
// EPI 2: f32 partial[z] +=   (L2 later chunks)   z splits K at ksplit
// EPI 3: f32 partial[z] store (L2 first chunk, iDFT with z=1 grid)
// ---------------------------------------------------------------------------
template <int EPI>
__global__ void gemm_mfma(const bf16* __restrict__ A, int lda,
                          const bf16* __restrict__ B, int ldb, size_t zBstride,
                          void* __restrict__ Cv, int ldc, size_t zCoff,
                          int N, int K, int ksplit,
                          const int* __restrict__ se2,
                          const float* __restrict__ biasR, const float* __restrict__ biasI,
                          int zBias, const float* __restrict__ gate8) {
    __shared__ bf16 As[128 * 32];
    __shared__ bf16 Bs[128 * 32];
    int tid = threadIdx.x;
    int zz = blockIdx.z;
    int row0 = blockIdx.y * 128, col0 = blockIdx.x * 128;
    const bf16* Bz = B + (size_t)zz * zBstride;

    int kS = 0, kE = K;
    if (EPI == 1) { int s = se2[2 * zz], e = se2[2 * zz + 1]; kS = (2 * s) & ~31; kE = (2 * e + 31) & ~31; }
    if (EPI == 2 || EPI == 3) { if (zz == 0) kE = ksplit; else kS = ksplit; }

    f32x4 acc[4][4] = {};

    int lane = tid & 63, wid = tid >> 6;
    int wrB = (wid >> 1) << 6, wcB = (wid & 1) << 6;
    int lr = lane & 15, lk = (lane >> 4) << 3;

    int r_a = tid >> 2, c_a = (tid & 3) << 3;
    int r_b = (tid + 256) >> 2, c_b = ((tid + 256) & 3) << 3;

    for (int kt = kS; kt < kE; kt += 32) {
        gload16(A + (size_t)(row0 + r_a) * lda + kt + c_a, &As[(size_t)tid * 8]);
        gload16(A + (size_t)(row0 + r_b) * lda + kt + c_b, &As[((size_t)tid + 256) * 8]);
        gload16(Bz + (size_t)(col0 + r_a) * ldb + kt + c_a, &Bs[(size_t)tid * 8]);
        gload16(Bz + (size_t)(col0 + r_b) * ldb + kt + c_b, &Bs[((size_t)tid + 256) * 8]);
        __syncthreads();
        short8 av[4], bv[4];
#pragma unroll
        for (int m = 0; m < 4; m++)
            av[m] = *(const short8*)&As[(wrB + m * 16 + lr) * 32 + lk];
#pragma unroll
        for (int n = 0; n < 4; n++)
            bv[n] = *(const short8*)&Bs[(wcB + n * 16 + lr) * 32 + lk];
#pragma unroll
        for (int m = 0; m < 4; m++)
#pragma unroll
            for (int n = 0; n < 4; n++)
                acc[m][n] = __builtin_amdgcn_mfma_f32_16x16x32_bf16(av[m], bv[n], acc[m][n], 0, 0, 0);
        __syncthreads();
    }

    int r0 = row0 + wrB + ((lane >> 4) << 2);
    int c0i = col0 + wcB + (lane & 15);
    float g = (EPI == 1) ? gate8[(row0 >> 7) * NE + zz] : 0.0f;

#pragma unroll
    for (int m = 0; m < 4; m++)
#pragma unroll
        for (int n = 0; n < 4; n++) {
            int c = c0i + n * 16;
            if (c >= N) continue;
#pragma unroll
            for (int j = 0; j < 4; j++) {
                int r = r0 + m * 16 + j;
                float v = acc[m][n][j];
                if (EPI == 0) {
                    ((bf16*)Cv)[(size_t)r * ldc + c] = f2b(v);
                } else if (EPI == 1) {
                    v += (c < HD) ? biasR[zz * zBias + c] : biasI[zz * zBias + c - HD];
                    v = fmaxf(v, 0.0f) * g;
                    ((bf16*)Cv + (size_t)zz * zCoff)[(size_t)r * ldc + c] = f2b(v);
                } else if (EPI == 3) {
                    ((float*)Cv + (size_t)zz * zCoff)[(size_t)r * ldc + c] = v;
                } else {
                    ((float*)Cv + (size_t)zz * zCoff)[(size_t)r * ldc + c] += v;
                }
            }
        }
}

// ---------------------------------------------------------------------------
extern "C" void kernel_launch(void* const* d_in, const int* in_sizes, int n_in,
                              void* d_out, int out_size, void* d_ws, size_t ws_size,
                              hipStream_t stream) {
    const float* X   = (const float*)d_in[0];
    const float* bp  = (const float*)d_in[1];
    const float* W1r = (const float*)d_in[2];
    const float* W1i = (const float*)d_in[3];
    const float* b1r = (const float*)d_in[4];
    const float* b1i = (const float*)d_in[5];
    const float* W2r = (const float*)d_in[6];
    const float* W2i = (const float*)d_in[7];
    const float* b2r = (const float*)d_in[8];
    const float* b2i = (const float*)d_in[9];
    const float* gW  = (const float*)d_in[10];
    const float* gb  = (const float*)d_in[11];
    float* out = (float*)d_out;

    // ---- choose chunk/splitk from ws_size (constant per session -> deterministic)
    const size_t FIXED = 97129984;                       // sum of aligned fixed buffers below
    const size_t SZP = (size_t)MR * XINT_LD * 4;         // 17301504
    const size_t SZH = (size_t)MR * HP_LD * 2;           // 17039360
    int chunk = 1, splitk = 1;
    {
        const int copt[5] = {8, 4, 2, 1, 1};
        const int sopt[5] = {2, 2, 2, 2, 1};
        for (int i = 0; i < 5; i++) {
            size_t need = FIXED + (size_t)sopt[i] * SZP + (size_t)copt[i] * SZH;
            if (need <= ws_size) { chunk = copt[i]; splitk = sopt[i]; break; }
        }
    }

    // ---- carve workspace
    char* p = (char*)d_ws;
    auto alloc = [&](size_t bytes) -> char* {
        char* r = p; p += (bytes + 255) & ~255ULL; return r;
    };
    int*   se    = (int*)alloc(64 * 4);
    float* mag   = (float*)alloc((size_t)BATCH * FB * 4);
    float* gate  = (float*)alloc((size_t)BATCH * NE * 4);
    float* biasC = (float*)alloc((size_t)BATCH * XINT_LD * 4);
    bf16*  Ffwd  = (bf16*)alloc((size_t)FF_ROWS * NN * 2);
    bf16*  Finv  = (bf16*)alloc((size_t)NN * XINT_LD * 2);
    bf16*  B1    = (bf16*)alloc((size_t)NE * B1_ROWS * XINT_LD * 2);
    bf16*  B2    = (bf16*)alloc((size_t)B2_ROWS * KCAT * 2);
    bf16*  Xint  = (bf16*)alloc((size_t)MR * XINT_LD * 2);
    bf16*  XbCombb = (bf16*)alloc((size_t)MR * XINT_LD * 2);  // Xb (phase 1-2) then combb (phase 6-7)
    float* partial = (float*)alloc((size_t)splitk * SZP);
    bf16*  Hp    = (bf16*)alloc((size_t)chunk * SZH);
    bf16*  Xb    = XbCombb;
    bf16*  combb = XbCombb;

    // ---- prep / tables / packing
    prep_kernel<<<1, 64, 0, stream>>>(bp, se);
    convert_X<<<(unsigned)(((size_t)MR * NN / 4 + 255) / 256), 256, 0, stream>>>(X, Xb);
    {
        long tot = (long)FF_ROWS * NN + (long)NN * XINT_LD;
        gen_tables<<<(unsigned)((tot + 255) / 256), 256, 0, stream>>>(Ffwd, Finv);
    }
    {
        long tot = (long)NE * B1_ROWS * XINT_LD;
        pack_B1<<<(unsigned)((tot + 255) / 256), 256, 0, stream>>>(W1r, W1i, se, B1);
    }
    {
        long tot = (long)B2_ROWS * KCAT;
        pack_B2<<<(unsigned)((tot + 255) / 256), 256, 0, stream>>>(W2r, W2i, B2);
    }

    // ---- forward DFT: Xint[4096][1056] = Xb * Ffwd^T (pad cols get 0 from zero B rows)
    gemm_mfma<0><<<dim3(9, 32, 1), 256, 0, stream>>>(
        Xb, NN, Ffwd, NN, 0, Xint, XINT_LD, 0, XINT_LD, NN, NN,
        nullptr, nullptr, nullptr, 0, nullptr);

    // ---- gate path
    mag_kernel<<<BATCH, 256, 0, stream>>>(Xint, mag);
    gate_kernel<<<BATCH, 64, 0, stream>>>(mag, gW, gb, gate);
    biasC_kernel<<<(BATCH * XINT_LD + 255) / 256, 256, 0, stream>>>(gate, b2r, b2i, biasC);

    // ---- expert chunks: L1 (batched over z=experts, gate folded) then L2 (K-concat, split-K)
    int nch = NE / chunk;
    for (int ci = 0; ci < nch; ci++) {
        int e0 = ci * chunk;
        gemm_mfma<1><<<dim3(17, 32, chunk), 256, 0, stream>>>(
            Xint, XINT_LD,
            B1 + (size_t)e0 * B1_ROWS * XINT_LD, XINT_LD, (size_t)B1_ROWS * XINT_LD,
            Hp, chunk * HP_LD, HP_LD,
            2 * HD, XINT_LD, 0,
            se + 2 * e0, b1r + (size_t)e0 * HD, b1i + (size_t)e0 * HD, HD, gate + e0);

        int Kc = chunk * HP_LD;
        int ksp = (splitk == 2) ? ((Kc / 2 + 31) & ~31) : Kc;
        if (ci == 0)
            gemm_mfma<3><<<dim3(9, 32, splitk), 256, 0, stream>>>(
                Hp, Kc, B2 + (size_t)e0 * HP_LD, KCAT, 0,
                partial, XINT_LD, (size_t)MR * XINT_LD,
                2 * FB, Kc, ksp, nullptr, nullptr, nullptr, 0, nullptr);
        else
            gemm_mfma<2><<<dim3(9, 32, splitk), 256, 0, stream>>>(
                Hp, Kc, B2 + (size_t)e0 * HP_LD, KCAT, 0,
                partial, XINT_LD, (size_t)MR * XINT_LD,
                2 * FB, Kc, ksp, nullptr, nullptr, nullptr, 0, nullptr);
    }

    // ---- reduce partials + gated bias -> bf16 combb
    reduce_comb<<<(unsigned)(((size_t)MR * XINT_LD + 255) / 256), 256, 0, stream>>>(
        partial, splitk, biasC, combb);

    // ---- inverse DFT: out[4096][1024] = combb * Finv^T (f32 store)
    gemm_mfma<3><<<dim3(8, 32, 1), 256, 0, stream>>>(
        combb, XINT_LD, Finv, XINT_LD, 0, out, NN, 0, NN, XINT_LD, XINT_LD,
        nullptr, nullptr, nullptr, 0, nullptr);
}

// Round 4
// 575.252 us; speedup vs baseline: 14.6913x; 1.1456x over previous
//
#include <hip/hip_runtime.h>
#include <hip/hip_bf16.h>
#include <math.h>

typedef __hip_bfloat16 bf16;
typedef __attribute__((ext_vector_type(8))) short short8;
typedef __attribute__((ext_vector_type(4))) float f32x4;

#define FB 513
#define HD 1026
#define NN 1024
#define MR 4096      // 32*128 rows
#define NE 8
#define BATCH 32

#define XINT_LD 1056   // 2*FB=1026 padded to 33*32
#define HP_LD   2080   // 2*HD=2052 padded (per-expert window in H')
#define B1_ROWS 2176   // 17*128 (N=2052)
#define B2_ROWS 1152   // 9*128  (N=1026)
#define FF_ROWS 1152   // 9*128
#define KCAT    16640  // 8*2080

__device__ __forceinline__ void gload16(const void* g, void* l) {
    __builtin_amdgcn_global_load_lds((const __attribute__((address_space(1))) void*)g,
                                     (__attribute__((address_space(3))) void*)l, 16, 0, 0);
}
__device__ __forceinline__ bf16 f2b(float v) { return __float2bfloat16(v); }

// XCD-aware bijective remap (requires gridDim.x*gridDim.y % 8 == 0).
// Consecutive orig ids round-robin XCDs; this gives XCD k a contiguous wg
// range so col-tile readers of the same A row-panel share one XCD L2.
__device__ __forceinline__ void xcd_swizzle(int* px, int* py) {
    int gx = gridDim.x;
    int orig = blockIdx.x + gx * blockIdx.y;
    int q = (gx * gridDim.y) >> 3;
    int wg = (orig & 7) * q + (orig >> 3);
    *px = wg % gx;
    *py = wg / gx;
}

// ---------------------------------------------------------------------------
__global__ void prep_kernel(const float* __restrict__ bp, int* __restrict__ se) {
    if (threadIdx.x == 0 && blockIdx.x == 0) {
        float b[9];
        b[0] = 0.0f; b[8] = 1.0f;
        for (int i = 0; i < 7; i++) b[i + 1] = 1.0f / (1.0f + expf(-bp[i]));
        for (int i = 1; i < 9; i++) { float v = b[i]; int j = i - 1;
            while (j >= 0 && b[j] > v) { b[j + 1] = b[j]; j--; } b[j + 1] = v; }
        int idx[9];
        for (int i = 0; i < 9; i++) idx[i] = (int)(b[i] * (float)(FB - 1));
        for (int e = 0; e < NE; e++) {
            se[2 * e] = idx[e];
            se[2 * e + 1] = (e < NE - 1) ? idx[e + 1] : FB;
        }
    }
}

// ---------------------------------------------------------------------------
__global__ void convert_X(const float* __restrict__ X, bf16* __restrict__ Xb) {
    long i = ((long)blockIdx.x * 256 + threadIdx.x) * 4;
    if (i >= (long)MR * NN) return;
    float4 v = *(const float4*)(X + i);
    bf16* o = Xb + i;
    o[0] = f2b(v.x); o[1] = f2b(v.y); o[2] = f2b(v.z); o[3] = f2b(v.w);
}

// ---------------------------------------------------------------------------
// Ffwd[1152][1024] rows 2f=cos, 2f+1=-sin ; Finv[1024][1056] cols 2f=c_f*cos/N, 2f+1=-c_f*sin/N
// ---------------------------------------------------------------------------
__global__ void gen_tables(bf16* __restrict__ Ffwd, bf16* __restrict__ Finv) {
    long i = (long)blockIdx.x * 256 + threadIdx.x;
    const long nF = (long)FF_ROWS * NN, nI = (long)NN * XINT_LD;
    const float TWO_PI = 6.283185307179586f;
    if (i < nF) {
        int n = (int)(i >> 10), t = (int)(i & (NN - 1));
        float v = 0.0f;
        if (n < 2 * FB) {
            int f = n >> 1, k = (f * t) & (NN - 1);
            float s, c; sincosf(TWO_PI * (float)k / (float)NN, &s, &c);
            v = (n & 1) ? -s : c;
        }
        Ffwd[i] = f2b(v);
    } else if (i < nF + nI) {
        long j = i - nF;
        int t = (int)(j / XINT_LD), k = (int)(j % XINT_LD);
        float v = 0.0f;
        if (k < 2 * FB) {
            int f = k >> 1, kk = (f * t) & (NN - 1);
            float s, c; sincosf(TWO_PI * (float)kk / (float)NN, &s, &c);
            float cf = (f == 0 || f == FB - 1) ? 1.0f : 2.0f;
            float sc = cf * (1.0f / (float)NN);
            v = (k & 1) ? -s * sc : c * sc;
        }
        Finv[j] = f2b(v);
    }
}

// ---------------------------------------------------------------------------
__global__ void pack_B1(const float* __restrict__ W1r, const float* __restrict__ W1i,
                        const int* __restrict__ se, bf16* __restrict__ B1) {
    long i = (long)blockIdx.x * 256 + threadIdx.x;
    const long total = (long)NE * B1_ROWS * XINT_LD;
    if (i >= total) return;
    int k = (int)(i % XINT_LD);
    long t = i / XINT_LD;
    int n = (int)(t % B1_ROWS);
    int e = (int)(t / B1_ROWS);
    float v = 0.0f;
    int f = k >> 1;
    if (n < 2 * HD && k < 2 * FB && f >= se[2 * e] && f < se[2 * e + 1]) {
        int hi_part = (n >= HD);
        int h = hi_part ? n - HD : n;
        long wi = ((long)e * HD + h) * FB + f;
        float wr = W1r[wi], wim = W1i[wi];
        v = (k & 1) ? (hi_part ? wr : -wim) : (hi_part ? wim : wr);
    }
    B1[i] = f2b(v);
}

// ---------------------------------------------------------------------------
__global__ void pack_B2(const float* __restrict__ W2r, const float* __restrict__ W2i,
                        bf16* __restrict__ B2) {
    long i = (long)blockIdx.x * 256 + threadIdx.x;
    const long total = (long)B2_ROWS * KCAT;
    if (i >= total) return;
    int col = (int)(i % KCAT);
    int n = (int)(i / KCAT);
    int e = col / HP_LD, k = col % HP_LD;
    float v = 0.0f;
    if (n < 2 * FB && k < 2 * HD) {
        int f = n >> 1, yi = n & 1;
        int hi_part = (k >= HD);
        int h = hi_part ? k - HD : k;
        long wi = ((long)e * FB + f) * HD + h;
        float wr = W2r[wi], wim = W2i[wi];
        v = yi ? (hi_part ? wr : wim) : (hi_part ? -wim : wr);
    }
    B2[i] = f2b(v);
}

// ---------------------------------------------------------------------------
__global__ void mag_kernel(const bf16* __restrict__ Xint, float* __restrict__ mag) {
    int b = blockIdx.x, t = threadIdx.x;
    float acc[3] = {0.0f, 0.0f, 0.0f};
    const bf16* base = Xint + (size_t)b * 128 * XINT_LD;
    for (int c = 0; c < 128; c++) {
        const bf16* row = base + (size_t)c * XINT_LD;
#pragma unroll
        for (int kk = 0; kk < 3; kk++) {
            int f = t + 256 * kk;
            if (f < FB) {
                float xr = __bfloat162float(row[2 * f]);
                float xi = __bfloat162float(row[2 * f + 1]);
                acc[kk] += sqrtf(xr * xr + xi * xi);
            }
        }
    }
#pragma unroll
    for (int kk = 0; kk < 3; kk++) {
        int f = t + 256 * kk;
        if (f < FB) mag[b * FB + f] = acc[kk] * (1.0f / 128.0f);
    }
}

// ---------------------------------------------------------------------------
__global__ void gate_kernel(const float* __restrict__ mag, const float* __restrict__ gW,
                            const float* __restrict__ gb, float* __restrict__ gate) {
    int b = blockIdx.x, lane = threadIdx.x;
    int e = lane & 7, j = lane >> 3;
    float acc = 0.0f;
    for (int f = j; f < FB; f += 8) acc += mag[b * FB + f] * gW[e * FB + f];
    acc += __shfl_xor(acc, 8); acc += __shfl_xor(acc, 16); acc += __shfl_xor(acc, 32);
    float logit = acc + gb[e];
    float mx = logit;
    mx = fmaxf(mx, __shfl_xor(mx, 1)); mx = fmaxf(mx, __shfl_xor(mx, 2)); mx = fmaxf(mx, __shfl_xor(mx, 4));
    float ex = expf(logit - mx);
    float sum = ex;
    sum += __shfl_xor(sum, 1); sum += __shfl_xor(sum, 2); sum += __shfl_xor(sum, 4);
    if (lane < 8) gate[b * NE + e] = ex / sum;
}

// ---------------------------------------------------------------------------
__global__ void biasC_kernel(const float* __restrict__ gate, const float* __restrict__ b2r,
                             const float* __restrict__ b2i, float* __restrict__ biasC) {
    int i = blockIdx.x * 256 + threadIdx.x;
    if (i >= BATCH * XINT_LD) return;
    int b = i / XINT_LD, c = i % XINT_LD;
    float v = 0.0f;
    if (c < 2 * FB) {
        int f = c >> 1;
        const float* bb = (c & 1) ? b2i : b2r;
#pragma unroll
        for (int e = 0; e < NE; e++) v += gate[b * NE + e] * bb[e * FB + f];
    }
    biasC[i] = v;
}

// ---------------------------------------------------------------------------
// combb[r][c] = bf16( sum_z partial[z][r][c] (+ biasC[b][c]) )  (c<1026 else 0)
// ---------------------------------------------------------------------------
__global__ void reduce_comb(const float* __restrict__ partial, int nplanes,
                            const float* __restrict__ biasC, bf16* __restrict__ combb) {
    long i = (long)blockIdx.x * 256 + threadIdx.x;
    if (i >= (long)MR * XINT_LD) return;
    int c = (int)(i % XINT_LD);
    long r = i / XINT_LD;
    float v = 0.0f;
    if (c < 2 * FB) {
        for (int z = 0; z < nplanes; z++) v += partial[(size_t)z * MR * XINT_LD + i];
        if (biasC) v += biasC[(int)(r >> 7) * XINT_LD + c];
    }
    combb[i] = f2b(v);
}

// ---------------------------------------------------------------------------
// out[i] = partial[0][i] + partial[1][i]   (iDFT split-K reduce, f32 [4096][1024])
// ---------------------------------------------------------------------------
__global__ void reduce_out(const float* __restrict__ partial, float* __restrict__ out) {
    long i = (long)blockIdx.x * 256 + threadIdx.x;
    if (i >= (long)MR * NN) return;
    out[i] = partial[i] + partial[(size_t)MR * NN + i];
}

// ---------------------------------------------------------------------------
// MFMA GEMM: C = A[4096][K]*B[N][K]^T (bf16 in, fp32 acc). 128x128 tile, BK=32,
// 4 waves, 4x4 mfma_f32_16x16x32_bf16. XCD-swizzled block mapping.
// EPI 0: store bf16
// EPI 1: per-z expert: K-range from se2[2z..], v=relu(acc+bias)*gate -> bf16 (L1)
// EPI 2: f32 partial[z] += ; z covers K-range [z*kPerZ, min(K,(z+1)*kPerZ))
// EPI 3: f32 partial[z] store (same z K-ranges)
// ---------------------------------------------------------------------------
template <int EPI>
__global__ void gemm_mfma(const bf16* __restrict__ A, int lda,
                          const bf16* __restrict__ B, int ldb, size_t zBstride,
                          void* __restrict__ Cv, int ldc, size_t zCoff,
                          int N, int K, int kPerZ,
                          const int* __restrict__ se2,
                          const float* __restrict__ biasR, const float* __restrict__ biasI,
                          int zBias, const float* __restrict__ gate8) {
    __shared__ bf16 As[128 * 32];
    __shared__ bf16 Bs[128 * 32];
    int tid = threadIdx.x;
    int zz = blockIdx.z;
    int bx, by;
    xcd_swizzle(&bx, &by);
    int row0 = by * 128, col0 = bx * 128;
    const bf16* Bz = B + (size_t)zz * zBstride;

    int kS = 0, kE = K;
    if (EPI == 1) { int s = se2[2 * zz], e = se2[2 * zz + 1]; kS = (2 * s) & ~31; kE = (2 * e + 31) & ~31; }
    if (EPI == 2 || EPI == 3) { kS = zz * kPerZ; kE = min(K, kS + kPerZ); }

    f32x4 acc[4][4] = {};

    int lane = tid & 63, wid = tid >> 6;
    int wrB = (wid >> 1) << 6, wcB = (wid & 1) << 6;
    int lr = lane & 15, lk = (lane >> 4) << 3;

    int r_a = tid >> 2, c_a = (tid & 3) << 3;
    int r_b = (tid + 256) >> 2, c_b = ((tid + 256) & 3) << 3;

    for (int kt = kS; kt < kE; kt += 32) {
        gload16(A + (size_t)(row0 + r_a) * lda + kt + c_a, &As[(size_t)tid * 8]);
        gload16(A + (size_t)(row0 + r_b) * lda + kt + c_b, &As[((size_t)tid + 256) * 8]);
        gload16(Bz + (size_t)(col0 + r_a) * ldb + kt + c_a, &Bs[(size_t)tid * 8]);
        gload16(Bz + (size_t)(col0 + r_b) * ldb + kt + c_b, &Bs[((size_t)tid + 256) * 8]);
        __syncthreads();
        short8 av[4], bv[4];
#pragma unroll
        for (int m = 0; m < 4; m++)
            av[m] = *(const short8*)&As[(wrB + m * 16 + lr) * 32 + lk];
#pragma unroll
        for (int n = 0; n < 4; n++)
            bv[n] = *(const short8*)&Bs[(wcB + n * 16 + lr) * 32 + lk];
#pragma unroll
        for (int m = 0; m < 4; m++)
#pragma unroll
            for (int n = 0; n < 4; n++)
                acc[m][n] = __builtin_amdgcn_mfma_f32_16x16x32_bf16(av[m], bv[n], acc[m][n], 0, 0, 0);
        __syncthreads();
    }

    int r0 = row0 + wrB + ((lane >> 4) << 2);
    int c0i = col0 + wcB + (lane & 15);
    float g = (EPI == 1) ? gate8[(row0 >> 7) * NE + zz] : 0.0f;

#pragma unroll
    for (int m = 0; m < 4; m++)
#pragma unroll
        for (int n = 0; n < 4; n++) {
            int c = c0i + n * 16;
            if (c >= N) continue;
#pragma unroll
            for (int j = 0; j < 4; j++) {
                int r = r0 + m * 16 + j;
                float v = acc[m][n][j];
                if (EPI == 0) {
                    ((bf16*)Cv)[(size_t)r * ldc + c] = f2b(v);
                } else if (EPI == 1) {
                    v += (c < HD) ? biasR[zz * zBias + c] : biasI[zz * zBias + c - HD];
                    v = fmaxf(v, 0.0f) * g;
                    ((bf16*)Cv + (size_t)zz * zCoff)[(size_t)r * ldc + c] = f2b(v);
                } else if (EPI == 3) {
                    ((float*)Cv + (size_t)zz * zCoff)[(size_t)r * ldc + c] = v;
                } else {
                    ((float*)Cv + (size_t)zz * zCoff)[(size_t)r * ldc + c] += v;
                }
            }
        }
}

// ---------------------------------------------------------------------------
extern "C" void kernel_launch(void* const* d_in, const int* in_sizes, int n_in,
                              void* d_out, int out_size, void* d_ws, size_t ws_size,
                              hipStream_t stream) {
    const float* X   = (const float*)d_in[0];
    const float* bp  = (const float*)d_in[1];
    const float* W1r = (const float*)d_in[2];
    const float* W1i = (const float*)d_in[3];
    const float* b1r = (const float*)d_in[4];
    const float* b1i = (const float*)d_in[5];
    const float* W2r = (const float*)d_in[6];
    const float* W2i = (const float*)d_in[7];
    const float* b2r = (const float*)d_in[8];
    const float* b2i = (const float*)d_in[9];
    const float* gW  = (const float*)d_in[10];
    const float* gb  = (const float*)d_in[11];
    float* out = (float*)d_out;

    // ---- choose chunk/splitk from ws_size (constant per session -> deterministic)
    const size_t FIXED = 97129984;
    const size_t SZP = (size_t)MR * XINT_LD * 4;         // 17301504
    const size_t SZH = (size_t)MR * HP_LD * 2;           // 17039360
    int chunk = 1, splitk = 1;
    {
        const int copt[6] = {8, 8, 4, 2, 1, 1};
        const int sopt[6] = {4, 2, 2, 2, 2, 1};
        for (int i = 0; i < 6; i++) {
            size_t need = FIXED + (size_t)sopt[i] * SZP + (size_t)copt[i] * SZH;
            if (need <= ws_size) { chunk = copt[i]; splitk = sopt[i]; break; }
        }
    }

    // ---- carve workspace
    char* p = (char*)d_ws;
    auto alloc = [&](size_t bytes) -> char* {
        char* r = p; p += (bytes + 255) & ~255ULL; return r;
    };
    int*   se    = (int*)alloc(64 * 4);
    float* mag   = (float*)alloc((size_t)BATCH * FB * 4);
    float* gate  = (float*)alloc((size_t)BATCH * NE * 4);
    float* biasC = (float*)alloc((size_t)BATCH * XINT_LD * 4);
    bf16*  Ffwd  = (bf16*)alloc((size_t)FF_ROWS * NN * 2);
    bf16*  Finv  = (bf16*)alloc((size_t)NN * XINT_LD * 2);
    bf16*  B1    = (bf16*)alloc((size_t)NE * B1_ROWS * XINT_LD * 2);
    bf16*  B2    = (bf16*)alloc((size_t)B2_ROWS * KCAT * 2);
    bf16*  Xint  = (bf16*)alloc((size_t)MR * XINT_LD * 2);
    bf16*  XbCombb = (bf16*)alloc((size_t)MR * XINT_LD * 2);  // Xb early, combb late
    float* partial = (float*)alloc((size_t)splitk * SZP);
    bf16*  Hp    = (bf16*)alloc((size_t)chunk * SZH);
    bf16*  Xb    = XbCombb;
    bf16*  combb = XbCombb;

    // ---- prep / tables / packing
    prep_kernel<<<1, 64, 0, stream>>>(bp, se);
    convert_X<<<(unsigned)(((size_t)MR * NN / 4 + 255) / 256), 256, 0, stream>>>(X, Xb);
    {
        long tot = (long)FF_ROWS * NN + (long)NN * XINT_LD;
        gen_tables<<<(unsigned)((tot + 255) / 256), 256, 0, stream>>>(Ffwd, Finv);
    }
    {
        long tot = (long)NE * B1_ROWS * XINT_LD;
        pack_B1<<<(unsigned)((tot + 255) / 256), 256, 0, stream>>>(W1r, W1i, se, B1);
    }
    {
        long tot = (long)B2_ROWS * KCAT;
        pack_B2<<<(unsigned)((tot + 255) / 256), 256, 0, stream>>>(W2r, W2i, B2);
    }

    // ---- forward DFT: Xint = Xb * Ffwd^T  (split-K over 2 partials when available)
    if (splitk >= 2) {
        gemm_mfma<3><<<dim3(9, 32, 2), 256, 0, stream>>>(
            Xb, NN, Ffwd, NN, 0, partial, XINT_LD, (size_t)MR * XINT_LD,
            XINT_LD, NN, 512, nullptr, nullptr, nullptr, 0, nullptr);
        reduce_comb<<<(unsigned)(((size_t)MR * XINT_LD + 255) / 256), 256, 0, stream>>>(
            partial, 2, nullptr, Xint);
    } else {
        gemm_mfma<0><<<dim3(9, 32, 1), 256, 0, stream>>>(
            Xb, NN, Ffwd, NN, 0, Xint, XINT_LD, 0, XINT_LD, NN, NN,
            nullptr, nullptr, nullptr, 0, nullptr);
    }

    // ---- gate path
    mag_kernel<<<BATCH, 256, 0, stream>>>(Xint, mag);
    gate_kernel<<<BATCH, 64, 0, stream>>>(mag, gW, gb, gate);
    biasC_kernel<<<(BATCH * XINT_LD + 255) / 256, 256, 0, stream>>>(gate, b2r, b2i, biasC);

    // ---- expert chunks: L1 (batched, gate folded) then L2 (K-concat, split-K)
    int nch = NE / chunk;
    for (int ci = 0; ci < nch; ci++) {
        int e0 = ci * chunk;
        gemm_mfma<1><<<dim3(17, 32, chunk), 256, 0, stream>>>(
            Xint, XINT_LD,
            B1 + (size_t)e0 * B1_ROWS * XINT_LD, XINT_LD, (size_t)B1_ROWS * XINT_LD,
            Hp, chunk * HP_LD, HP_LD,
            2 * HD, XINT_LD, 0,
            se + 2 * e0, b1r + (size_t)e0 * HD, b1i + (size_t)e0 * HD, HD, gate + e0);

        int Kc = chunk * HP_LD;
        int kPerZ = ((Kc / splitk) + 31) & ~31;
        if (ci == 0)
            gemm_mfma<3><<<dim3(9, 32, splitk), 256, 0, stream>>>(
                Hp, Kc, B2 + (size_t)e0 * HP_LD, KCAT, 0,
                partial, XINT_LD, (size_t)MR * XINT_LD,
                2 * FB, Kc, kPerZ, nullptr, nullptr, nullptr, 0, nullptr);
        else
            gemm_mfma<2><<<dim3(9, 32, splitk), 256, 0, stream>>>(
                Hp, Kc, B2 + (size_t)e0 * HP_LD, KCAT, 0,
                partial, XINT_LD, (size_t)MR * XINT_LD,
                2 * FB, Kc, kPerZ, nullptr, nullptr, nullptr, 0, nullptr);
    }

    // ---- reduce partials + gated bias -> bf16 combb
    reduce_comb<<<(unsigned)(((size_t)MR * XINT_LD + 255) / 256), 256, 0, stream>>>(
        partial, splitk, biasC, combb);

    // ---- inverse DFT: out = combb * Finv^T (split-K when partial space exists)
    if (splitk >= 2) {
        gemm_mfma<3><<<dim3(8, 32, 2), 256, 0, stream>>>(
            combb, XINT_LD, Finv, XINT_LD, 0, partial, NN, (size_t)MR * NN,
            NN, XINT_LD, 544, nullptr, nullptr, nullptr, 0, nullptr);
        reduce_out<<<(unsigned)(((size_t)MR * NN + 255) / 256), 256, 0, stream>>>(partial, out);
    } else {
        gemm_mfma<3><<<dim3(8, 32, 1), 256, 0, stream>>>(
            combb, XINT_LD, Finv, XINT_LD, 0, out, NN, 0, NN, XINT_LD, XINT_LD,
            nullptr, nullptr, nullptr, 0, nullptr);
    }
}

// Round 5
// 563.600 us; speedup vs baseline: 14.9950x; 1.0207x over previous
//
#include <hip/hip_runtime.h>
#include <hip/hip_bf16.h>
#include <math.h>

typedef __hip_bfloat16 bf16;
typedef __attribute__((ext_vector_type(8))) short short8;
typedef __attribute__((ext_vector_type(4))) float f32x4;

#define FB 513
#define HD 1026
#define NN 1024
#define MR 4096      // 32*128 rows
#define NE 8
#define BATCH 32

#define XINT_LD 1056   // 2*FB=1026 padded to 33*32
#define HP_LD   2080   // 2*HD=2052 padded (per-expert window in H')
#define B1_ROWS 2176   // 17*128 (N=2052)
#define B2_ROWS 1152   // 9*128  (N=1026)
#define FF_ROWS 1152   // 9*128
#define KCAT    16640  // 8*2080
#define MAG_LD  520    // 513 padded

__device__ __forceinline__ void gload16(const void* g, void* l) {
    __builtin_amdgcn_global_load_lds((const __attribute__((address_space(1))) void*)g,
                                     (__attribute__((address_space(3))) void*)l, 16, 0, 0);
}
__device__ __forceinline__ bf16 f2b(float v) { return __float2bfloat16(v); }

// XCD-aware bijective remap (requires gridDim.x*gridDim.y % 8 == 0).
__device__ __forceinline__ void xcd_swizzle(int* px, int* py) {
    int gx = gridDim.x;
    int orig = blockIdx.x + gx * blockIdx.y;
    int q = (gx * gridDim.y) >> 3;
    int wg = (orig & 7) * q + (orig >> 3);
    *px = wg % gx;
    *py = wg / gx;
}

// ---------------------------------------------------------------------------
__global__ void prep_kernel(const float* __restrict__ bp, int* __restrict__ se) {
    if (threadIdx.x == 0 && blockIdx.x == 0) {
        float b[9];
        b[0] = 0.0f; b[8] = 1.0f;
        for (int i = 0; i < 7; i++) b[i + 1] = 1.0f / (1.0f + expf(-bp[i]));
        for (int i = 1; i < 9; i++) { float v = b[i]; int j = i - 1;
            while (j >= 0 && b[j] > v) { b[j + 1] = b[j]; j--; } b[j + 1] = v; }
        int idx[9];
        for (int i = 0; i < 9; i++) idx[i] = (int)(b[i] * (float)(FB - 1));
        for (int e = 0; e < NE; e++) {
            se[2 * e] = idx[e];
            se[2 * e + 1] = (e < NE - 1) ? idx[e + 1] : FB;
        }
    }
}

// ---------------------------------------------------------------------------
// Fused elementwise prep: [tables | pack_B1 | pack_B2 | convert_X] by index range.
// ---------------------------------------------------------------------------
#define N_TAB  (2260992L)                       // 1152*1024 + 1024*1056
#define N_B1   ((long)NE * B1_ROWS * XINT_LD)   // 18382848
#define N_B2   ((long)B2_ROWS * KCAT)           // 19169280
#define N_X    ((long)MR * NN)                  // 4194304
__global__ void prep_bulk(const float* __restrict__ W1r, const float* __restrict__ W1i,
                          const float* __restrict__ W2r, const float* __restrict__ W2i,
                          const float* __restrict__ X, const int* __restrict__ se,
                          bf16* __restrict__ Ffwd, bf16* __restrict__ Finv,
                          bf16* __restrict__ B1, bf16* __restrict__ B2,
                          bf16* __restrict__ Xb) {
    long i = (long)blockIdx.x * 256 + threadIdx.x;
    const float TWO_PI = 6.283185307179586f;
    const long nF = (long)FF_ROWS * NN;
    if (i < nF) {
        int n = (int)(i >> 10), t = (int)(i & (NN - 1));
        float v = 0.0f;
        if (n < 2 * FB) {
            int f = n >> 1, k = (f * t) & (NN - 1);
            float s, c; sincosf(TWO_PI * (float)k / (float)NN, &s, &c);
            v = (n & 1) ? -s : c;
        }
        Ffwd[i] = f2b(v);
        return;
    }
    i -= nF;
    const long nI = (long)NN * XINT_LD;
    if (i < nI) {
        int t = (int)(i / XINT_LD), k = (int)(i % XINT_LD);
        float v = 0.0f;
        if (k < 2 * FB) {
            int f = k >> 1, kk = (f * t) & (NN - 1);
            float s, c; sincosf(TWO_PI * (float)kk / (float)NN, &s, &c);
            float cf = (f == 0 || f == FB - 1) ? 1.0f : 2.0f;
            float sc = cf * (1.0f / (float)NN);
            v = (k & 1) ? -s * sc : c * sc;
        }
        Finv[i] = f2b(v);
        return;
    }
    i -= nI;
    if (i < N_B1) {
        int k = (int)(i % XINT_LD);
        long t = i / XINT_LD;
        int n = (int)(t % B1_ROWS);
        int e = (int)(t / B1_ROWS);
        float v = 0.0f;
        int f = k >> 1;
        if (n < 2 * HD && k < 2 * FB && f >= se[2 * e] && f < se[2 * e + 1]) {
            int hi_part = (n >= HD);
            int h = hi_part ? n - HD : n;
            long wi = ((long)e * HD + h) * FB + f;
            float wr = W1r[wi], wim = W1i[wi];
            v = (k & 1) ? (hi_part ? wr : -wim) : (hi_part ? wim : wr);
        }
        B1[i] = f2b(v);
        return;
    }
    i -= N_B1;
    if (i < N_B2) {
        int col = (int)(i % KCAT);
        int n = (int)(i / KCAT);
        int e = col / HP_LD, k = col % HP_LD;
        float v = 0.0f;
        if (n < 2 * FB && k < 2 * HD) {
            int f = n >> 1, yi = n & 1;
            int hi_part = (k >= HD);
            int h = hi_part ? k - HD : k;
            long wi = ((long)e * FB + f) * HD + h;
            float wr = W2r[wi], wim = W2i[wi];
            v = yi ? (hi_part ? wr : wim) : (hi_part ? -wim : wr);
        }
        B2[i] = f2b(v);
        return;
    }
    i -= N_B2;
    if (i < N_X) Xb[i] = f2b(X[i]);
}

// ---------------------------------------------------------------------------
// magp[b][g][f] = sum over 16 channels of |Xf|; grid (32,8)
// ---------------------------------------------------------------------------
__global__ void mag_kernel(const bf16* __restrict__ Xint, float* __restrict__ magp) {
    int b = blockIdx.x, g = blockIdx.y, t = threadIdx.x;
    float acc[3] = {0.0f, 0.0f, 0.0f};
    const bf16* base = Xint + ((size_t)b * 128 + g * 16) * XINT_LD;
    for (int c = 0; c < 16; c++) {
        const bf16* row = base + (size_t)c * XINT_LD;
#pragma unroll
        for (int kk = 0; kk < 3; kk++) {
            int f = t + 256 * kk;
            if (f < FB) {
                float xr = __bfloat162float(row[2 * f]);
                float xi = __bfloat162float(row[2 * f + 1]);
                acc[kk] += sqrtf(xr * xr + xi * xi);
            }
        }
    }
#pragma unroll
    for (int kk = 0; kk < 3; kk++) {
        int f = t + 256 * kk;
        if (f < FB) magp[((size_t)b * 8 + g) * MAG_LD + f] = acc[kk];
    }
}

// ---------------------------------------------------------------------------
__global__ void gate_kernel(const float* __restrict__ magp, const float* __restrict__ gW,
                            const float* __restrict__ gb, float* __restrict__ gate) {
    int b = blockIdx.x, lane = threadIdx.x;
    int e = lane & 7, j = lane >> 3;
    float acc = 0.0f;
    for (int f = j; f < FB; f += 8) {
        float m = 0.0f;
#pragma unroll
        for (int g = 0; g < 8; g++) m += magp[((size_t)b * 8 + g) * MAG_LD + f];
        acc += m * (1.0f / 128.0f) * gW[e * FB + f];
    }
    acc += __shfl_xor(acc, 8); acc += __shfl_xor(acc, 16); acc += __shfl_xor(acc, 32);
    float logit = acc + gb[e];
    float mx = logit;
    mx = fmaxf(mx, __shfl_xor(mx, 1)); mx = fmaxf(mx, __shfl_xor(mx, 2)); mx = fmaxf(mx, __shfl_xor(mx, 4));
    float ex = expf(logit - mx);
    float sum = ex;
    sum += __shfl_xor(sum, 1); sum += __shfl_xor(sum, 2); sum += __shfl_xor(sum, 4);
    if (lane < 8) gate[b * NE + e] = ex / sum;
}

// ---------------------------------------------------------------------------
__global__ void biasC_kernel(const float* __restrict__ gate, const float* __restrict__ b2r,
                             const float* __restrict__ b2i, float* __restrict__ biasC) {
    int i = blockIdx.x * 256 + threadIdx.x;
    if (i >= BATCH * XINT_LD) return;
    int b = i / XINT_LD, c = i % XINT_LD;
    float v = 0.0f;
    if (c < 2 * FB) {
        int f = c >> 1;
        const float* bb = (c & 1) ? b2i : b2r;
#pragma unroll
        for (int e = 0; e < NE; e++) v += gate[b * NE + e] * bb[e * FB + f];
    }
    biasC[i] = v;
}

// ---------------------------------------------------------------------------
// combb[r][c] = bf16( sum_z partial[z][r][c] (+ biasC[b][c]) )  (c<1026 else 0)
// ---------------------------------------------------------------------------
__global__ void reduce_comb(const float* __restrict__ partial, int nplanes,
                            const float* __restrict__ biasC, bf16* __restrict__ combb) {
    long i = (long)blockIdx.x * 256 + threadIdx.x;
    if (i >= (long)MR * XINT_LD) return;
    int c = (int)(i % XINT_LD);
    long r = i / XINT_LD;
    float v = 0.0f;
    if (c < 2 * FB) {
        for (int z = 0; z < nplanes; z++) v += partial[(size_t)z * MR * XINT_LD + i];
        if (biasC) v += biasC[(int)(r >> 7) * XINT_LD + c];
    }
    combb[i] = f2b(v);
}

// ---------------------------------------------------------------------------
__global__ void reduce_out(const float* __restrict__ partial, int nplanes,
                           float* __restrict__ out) {
    long i = (long)blockIdx.x * 256 + threadIdx.x;
    if (i >= (long)MR * NN) return;
    float v = partial[i];
    for (int z = 1; z < nplanes; z++) v += partial[(size_t)z * MR * NN + i];
    out[i] = v;
}

// ---------------------------------------------------------------------------
// MFMA GEMM: C = A[4096][K]*B[N][K]^T (bf16 in, fp32 acc). 128x128 tile, BK=32,
// 4 waves, 4x4 mfma_f32_16x16x32_bf16. XCD-swizzled block mapping.
// EPI 0: store bf16
// EPI 1: per-z expert: K-range from se2[2z..], v=relu(acc+bias)*gate -> bf16 (L1)
// EPI 2: f32 partial[z] += ; z covers K-range [z*kPerZ, min(K,(z+1)*kPerZ))
// EPI 3: f32 partial[z] store (same z K-ranges)
// ---------------------------------------------------------------------------
template <int EPI>
__global__ void gemm_mfma(const bf16* __restrict__ A, int lda,
                          const bf16* __restrict__ B, int ldb, size_t zBstride,
                          void* __restrict__ Cv, int ldc, size_t zCoff,
                          int N, int K, int kPerZ,
                          const int* __restrict__ se2,
                          const float* __restrict__ biasR, const float* __restrict__ biasI,
                          int zBias, const float* __restrict__ gate8) {
    __shared__ bf16 As[128 * 32];
    __shared__ bf16 Bs[128 * 32];
    int tid = threadIdx.x;
    int zz = blockIdx.z;
    int bx, by;
    xcd_swizzle(&bx, &by);
    int row0 = by * 128, col0 = bx * 128;
    const bf16* Bz = B + (size_t)zz * zBstride;

    int kS = 0, kE = K;
    if (EPI == 1) { int s = se2[2 * zz], e = se2[2 * zz + 1]; kS = (2 * s) & ~31; kE = (2 * e + 31) & ~31; }
    if (EPI == 2 || EPI == 3) { kS = zz * kPerZ; kE = min(K, kS + kPerZ); }

    f32x4 acc[4][4] = {};

    int lane = tid & 63, wid = tid >> 6;
    int wrB = (wid >> 1) << 6, wcB = (wid & 1) << 6;
    int lr = lane & 15, lk = (lane >> 4) << 3;

    int r_a = tid >> 2, c_a = (tid & 3) << 3;
    int r_b = (tid + 256) >> 2, c_b = ((tid + 256) & 3) << 3;

    for (int kt = kS; kt < kE; kt += 32) {
        gload16(A + (size_t)(row0 + r_a) * lda + kt + c_a, &As[(size_t)tid * 8]);
        gload16(A + (size_t)(row0 + r_b) * lda + kt + c_b, &As[((size_t)tid + 256) * 8]);
        gload16(Bz + (size_t)(col0 + r_a) * ldb + kt + c_a, &Bs[(size_t)tid * 8]);
        gload16(Bz + (size_t)(col0 + r_b) * ldb + kt + c_b, &Bs[((size_t)tid + 256) * 8]);
        __syncthreads();
        short8 av[4], bv[4];
#pragma unroll
        for (int m = 0; m < 4; m++)
            av[m] = *(const short8*)&As[(wrB + m * 16 + lr) * 32 + lk];
#pragma unroll
        for (int n = 0; n < 4; n++)
            bv[n] = *(const short8*)&Bs[(wcB + n * 16 + lr) * 32 + lk];
#pragma unroll
        for (int m = 0; m < 4; m++)
#pragma unroll
            for (int n = 0; n < 4; n++)
                acc[m][n] = __builtin_amdgcn_mfma_f32_16x16x32_bf16(av[m], bv[n], acc[m][n], 0, 0, 0);
        __syncthreads();
    }

    int r0 = row0 + wrB + ((lane >> 4) << 2);
    int c0i = col0 + wcB + (lane & 15);
    float g = (EPI == 1) ? gate8[(row0 >> 7) * NE + zz] : 0.0f;

#pragma unroll
    for (int m = 0; m < 4; m++)
#pragma unroll
        for (int n = 0; n < 4; n++) {
            int c = c0i + n * 16;
            if (c >= N) continue;
#pragma unroll
            for (int j = 0; j < 4; j++) {
                int r = r0 + m * 16 + j;
                float v = acc[m][n][j];
                if (EPI == 0) {
                    ((bf16*)Cv)[(size_t)r * ldc + c] = f2b(v);
                } else if (EPI == 1) {
                    v += (c < HD) ? biasR[zz * zBias + c] : biasI[zz * zBias + c - HD];
                    v = fmaxf(v, 0.0f) * g;
                    ((bf16*)Cv + (size_t)zz * zCoff)[(size_t)r * ldc + c] = f2b(v);
                } else if (EPI == 3) {
                    ((float*)Cv + (size_t)zz * zCoff)[(size_t)r * ldc + c] = v;
                } else {
                    ((float*)Cv + (size_t)zz * zCoff)[(size_t)r * ldc + c] += v;
                }
            }
        }
}

// ---------------------------------------------------------------------------
extern "C" void kernel_launch(void* const* d_in, const int* in_sizes, int n_in,
                              void* d_out, int out_size, void* d_ws, size_t ws_size,
                              hipStream_t stream) {
    const float* X   = (const float*)d_in[0];
    const float* bp  = (const float*)d_in[1];
    const float* W1r = (const float*)d_in[2];
    const float* W1i = (const float*)d_in[3];
    const float* b1r = (const float*)d_in[4];
    const float* b1i = (const float*)d_in[5];
    const float* W2r = (const float*)d_in[6];
    const float* W2i = (const float*)d_in[7];
    const float* b2r = (const float*)d_in[8];
    const float* b2i = (const float*)d_in[9];
    const float* gW  = (const float*)d_in[10];
    const float* gb  = (const float*)d_in[11];
    float* out = (float*)d_out;

    // ---- choose chunk/splitk from ws_size (constant -> deterministic)
    const size_t FIXED = 98000000;                       // conservative fixed-buffer bound
    const size_t SZP = (size_t)MR * XINT_LD * 4;         // 17301504
    const size_t SZH = (size_t)MR * HP_LD * 2;           // 17039360
    int chunk = 1, splitk = 1;
    {
        const int copt[6] = {8, 4, 2, 1, 1, 1};
        const int sopt[6] = {4, 4, 4, 2, 2, 1};
        for (int i = 0; i < 6; i++) {
            size_t need = FIXED + (size_t)sopt[i] * SZP + (size_t)copt[i] * SZH;
            if (need <= ws_size) { chunk = copt[i]; splitk = sopt[i]; break; }
        }
    }

    // ---- carve workspace
    char* p = (char*)d_ws;
    auto alloc = [&](size_t bytes) -> char* {
        char* r = p; p += (bytes + 255) & ~255ULL; return r;
    };
    int*   se    = (int*)alloc(64 * 4);
    float* magp  = (float*)alloc((size_t)BATCH * 8 * MAG_LD * 4);
    float* gate  = (float*)alloc((size_t)BATCH * NE * 4);
    float* biasC = (float*)alloc((size_t)BATCH * XINT_LD * 4);
    bf16*  Ffwd  = (bf16*)alloc((size_t)FF_ROWS * NN * 2);
    bf16*  Finv  = (bf16*)alloc((size_t)NN * XINT_LD * 2);
    bf16*  B1    = (bf16*)alloc((size_t)NE * B1_ROWS * XINT_LD * 2);
    bf16*  B2    = (bf16*)alloc((size_t)B2_ROWS * KCAT * 2);
    bf16*  Xint  = (bf16*)alloc((size_t)MR * XINT_LD * 2);
    bf16*  XbCombb = (bf16*)alloc((size_t)MR * XINT_LD * 2);  // Xb early, combb late
    float* partial = (float*)alloc((size_t)splitk * SZP);
    bf16*  Hp    = (bf16*)alloc((size_t)chunk * SZH);
    bf16*  Xb    = XbCombb;
    bf16*  combb = XbCombb;

    // ---- prep (se first, then fused bulk packing/tables/convert)
    prep_kernel<<<1, 64, 0, stream>>>(bp, se);
    {
        long tot = N_TAB + N_B1 + N_B2 + N_X;
        prep_bulk<<<(unsigned)((tot + 255) / 256), 256, 0, stream>>>(
            W1r, W1i, W2r, W2i, X, se, Ffwd, Finv, B1, B2, Xb);
    }

    // ---- forward DFT: Xint = Xb * Ffwd^T  (split-K when partials exist)
    int zdft = (splitk >= 4) ? 4 : splitk;
    if (zdft >= 2) {
        int kPerZ = ((NN / zdft) + 31) & ~31;
        gemm_mfma<3><<<dim3(9, 32, zdft), 256, 0, stream>>>(
            Xb, NN, Ffwd, NN, 0, partial, XINT_LD, (size_t)MR * XINT_LD,
            XINT_LD, NN, kPerZ, nullptr, nullptr, nullptr, 0, nullptr);
        reduce_comb<<<(unsigned)(((size_t)MR * XINT_LD + 255) / 256), 256, 0, stream>>>(
            partial, zdft, nullptr, Xint);
    } else {
        gemm_mfma<0><<<dim3(9, 32, 1), 256, 0, stream>>>(
            Xb, NN, Ffwd, NN, 0, Xint, XINT_LD, 0, XINT_LD, NN, NN,
            nullptr, nullptr, nullptr, 0, nullptr);
    }

    // ---- gate path
    mag_kernel<<<dim3(BATCH, 8), 256, 0, stream>>>(Xint, magp);
    gate_kernel<<<BATCH, 64, 0, stream>>>(magp, gW, gb, gate);
    biasC_kernel<<<(BATCH * XINT_LD + 255) / 256, 256, 0, stream>>>(gate, b2r, b2i, biasC);

    // ---- expert chunks: L1 (batched, gate folded) then L2 (K-concat, split-K)
    int nch = NE / chunk;
    for (int ci = 0; ci < nch; ci++) {
        int e0 = ci * chunk;
        gemm_mfma<1><<<dim3(17, 32, chunk), 256, 0, stream>>>(
            Xint, XINT_LD,
            B1 + (size_t)e0 * B1_ROWS * XINT_LD, XINT_LD, (size_t)B1_ROWS * XINT_LD,
            Hp, chunk * HP_LD, HP_LD,
            2 * HD, XINT_LD, 0,
            se + 2 * e0, b1r + (size_t)e0 * HD, b1i + (size_t)e0 * HD, HD, gate + e0);

        int Kc = chunk * HP_LD;
        int kPerZ = ((Kc / splitk) + 31) & ~31;
        if (ci == 0)
            gemm_mfma<3><<<dim3(9, 32, splitk), 256, 0, stream>>>(
                Hp, Kc, B2 + (size_t)e0 * HP_LD, KCAT, 0,
                partial, XINT_LD, (size_t)MR * XINT_LD,
                2 * FB, Kc, kPerZ, nullptr, nullptr, nullptr, 0, nullptr);
        else
            gemm_mfma<2><<<dim3(9, 32, splitk), 256, 0, stream>>>(
                Hp, Kc, B2 + (size_t)e0 * HP_LD, KCAT, 0,
                partial, XINT_LD, (size_t)MR * XINT_LD,
                2 * FB, Kc, kPerZ, nullptr, nullptr, nullptr, 0, nullptr);
    }

    // ---- reduce partials + gated bias -> bf16 combb
    reduce_comb<<<(unsigned)(((size_t)MR * XINT_LD + 255) / 256), 256, 0, stream>>>(
        partial, splitk, biasC, combb);

    // ---- inverse DFT: out = combb * Finv^T (split-K when partial space exists)
    int ziv = (splitk >= 4) ? 4 : splitk;
    if (ziv >= 2) {
        int kPerZ = ((XINT_LD / ziv) + 31) & ~31;
        gemm_mfma<3><<<dim3(8, 32, ziv), 256, 0, stream>>>(
            combb, XINT_LD, Finv, XINT_LD, 0, partial, NN, (size_t)MR * NN,
            NN, XINT_LD, kPerZ, nullptr, nullptr, nullptr, 0, nullptr);
        reduce_out<<<(unsigned)(((size_t)MR * NN + 255) / 256), 256, 0, stream>>>(partial, ziv, out);
    } else {
        gemm_mfma<3><<<dim3(8, 32, 1), 256, 0, stream>>>(
            combb, XINT_LD, Finv, XINT_LD, 0, out, NN, 0, NN, XINT_LD, XINT_LD,
            nullptr, nullptr, nullptr, 0, nullptr);
    }
}

// Round 6
// 448.504 us; speedup vs baseline: 18.8431x; 1.2566x over previous
//
#include <hip/hip_runtime.h>
#include <hip/hip_bf16.h>
#include <math.h>

typedef __hip_bfloat16 bf16;
typedef __attribute__((ext_vector_type(8))) short short8;
typedef __attribute__((ext_vector_type(4))) short short4v;
typedef __attribute__((ext_vector_type(4))) float f32x4;

#define FB 513
#define HD 1026
#define NN 1024
#define MR 4096      // 32*128 rows
#define NE 8
#define BATCH 32

#define XINT_LD 1056   // 2*FB=1026 padded to 33*32
#define HP_LD   2080   // 2*HD=2052 padded (per-expert window in H')
#define B1_ROWS 2176   // 17*128 (N=2052)
#define B2_ROWS 1152   // 9*128  (N=1026)
#define KCAT    16640  // 8*2080
#define PLANE   ((size_t)MR * XINT_LD)   // elems per comb-plane

__device__ __forceinline__ void gload16(const void* g, void* l) {
    __builtin_amdgcn_global_load_lds((const __attribute__((address_space(1))) void*)g,
                                     (__attribute__((address_space(3))) void*)l, 16, 0, 0);
}
__device__ __forceinline__ bf16 f2b(float v) { return __float2bfloat16(v); }
__device__ __forceinline__ unsigned short f2bu(float v) {
    bf16 b = __float2bfloat16(v);
    return *reinterpret_cast<unsigned short*>(&b);
}
__device__ __forceinline__ float bu2f(unsigned short u) {
    return __uint_as_float(((unsigned)u) << 16);
}
__device__ __forceinline__ unsigned pack2(float a, float b) {
    return (unsigned)f2bu(a) | ((unsigned)f2bu(b) << 16);
}

// XCD-aware bijective remap (requires gridDim.x*gridDim.y % 8 == 0).
__device__ __forceinline__ void xcd_swizzle(int* px, int* py) {
    int gx = gridDim.x;
    int orig = blockIdx.x + gx * blockIdx.y;
    int q = (gx * gridDim.y) >> 3;
    int wg = (orig & 7) * q + (orig >> 3);
    *px = wg % gx;
    *py = wg / gx;
}

// ---------------------------------------------------------------------------
__global__ void prep_kernel(const float* __restrict__ bp, int* __restrict__ se) {
    if (threadIdx.x == 0 && blockIdx.x == 0) {
        float b[9];
        b[0] = 0.0f; b[8] = 1.0f;
        for (int i = 0; i < 7; i++) b[i + 1] = 1.0f / (1.0f + expf(-bp[i]));
        for (int i = 1; i < 9; i++) { float v = b[i]; int j = i - 1;
            while (j >= 0 && b[j] > v) { b[j + 1] = b[j]; j--; } b[j + 1] = v; }
        int idx[9];
        for (int i = 0; i < 9; i++) idx[i] = (int)(b[i] * (float)(FB - 1));
        for (int e = 0; e < NE; e++) {
            se[2 * e] = idx[e];
            se[2 * e + 1] = (e < NE - 1) ? idx[e + 1] : FB;
        }
    }
}

// ---------------------------------------------------------------------------
// Fused prep, paired packing: [Ffwd | Finv | B1 pairs | B2 row-pairs | X pairs]
// ---------------------------------------------------------------------------
#define N_FF  (1056L * 1024)                      // 1,081,344
#define N_FI  (1024L * 1056)                      // 1,081,344
#define N_B1P ((long)NE * B1_ROWS * (XINT_LD/2))  // 9,191,424
#define N_B2P ((long)(B2_ROWS/2) * KCAT)          // 9,584,640
#define N_XP  ((long)MR * NN / 2)                 // 2,097,152
#define N_PREP (N_FF + N_FI + N_B1P + N_B2P + N_XP)

__global__ void prep_bulk(const float* __restrict__ W1r, const float* __restrict__ W1i,
                          const float* __restrict__ W2r, const float* __restrict__ W2i,
                          const float* __restrict__ X, const int* __restrict__ se,
                          bf16* __restrict__ Ffwd, bf16* __restrict__ Finv,
                          bf16* __restrict__ B1, bf16* __restrict__ B2,
                          bf16* __restrict__ Xb) {
    long i = (long)blockIdx.x * 256 + threadIdx.x;
    const float TWO_PI = 6.283185307179586f;
    if (i < N_FF) {                 // Ffwd[1056][1024]: rows 2f=cos, 2f+1=-sin
        int n = (int)(i >> 10), t = (int)(i & (NN - 1));
        float v = 0.0f;
        if (n < 2 * FB) {
            int f = n >> 1, k = (f * t) & (NN - 1);
            float s, c; sincosf(TWO_PI * (float)k / (float)NN, &s, &c);
            v = (n & 1) ? -s : c;
        }
        Ffwd[i] = f2b(v);
        return;
    }
    i -= N_FF;
    if (i < N_FI) {                 // Finv[1024][1056]: cols 2f=c_f*cos/N, 2f+1=-c_f*sin/N
        int t = (int)(i / XINT_LD), k = (int)(i % XINT_LD);
        float v = 0.0f;
        if (k < 2 * FB) {
            int f = k >> 1, kk = (f * t) & (NN - 1);
            float s, c; sincosf(TWO_PI * (float)kk / (float)NN, &s, &c);
            float cf = (f == 0 || f == FB - 1) ? 1.0f : 2.0f;
            float sc = cf * (1.0f / (float)NN);
            v = (k & 1) ? -s * sc : c * sc;
        }
        Finv[i] = f2b(v);
        return;
    }
    i -= N_FI;
    if (i < N_B1P) {                // B1: pair (2f, 2f+1) per thread
        int f = (int)(i % (XINT_LD / 2));
        long t = i / (XINT_LD / 2);
        int n = (int)(t % B1_ROWS);
        int e = (int)(t / B1_ROWS);
        float ve = 0.0f, vo = 0.0f;
        if (n < 2 * HD && f < FB && f >= se[2 * e] && f < se[2 * e + 1]) {
            int hi_part = (n >= HD);
            int h = hi_part ? n - HD : n;
            long wi = ((long)e * HD + h) * FB + f;
            float wr = W1r[wi], wim = W1i[wi];
            ve = hi_part ? wim : wr;       // col 2f
            vo = hi_part ? wr : -wim;      // col 2f+1
        }
        *(unsigned*)(B1 + ((size_t)(e * B1_ROWS + n)) * XINT_LD + 2 * f) = pack2(ve, vo);
        return;
    }
    i -= N_B1P;
    if (i < N_B2P) {                // B2: row-pair (2f, 2f+1) per thread
        int col = (int)(i % KCAT);
        int f = (int)(i / KCAT);    // [0, 576)
        int e = col / HP_LD, k = col % HP_LD;
        float vr = 0.0f, vi_ = 0.0f;
        if (f < FB && k < 2 * HD) {
            int hi_part = (k >= HD);
            int h = hi_part ? k - HD : k;
            long wi = ((long)e * FB + f) * HD + h;
            float wr = W2r[wi], wim = W2i[wi];
            vr  = hi_part ? -wim : wr;     // row 2f  (yr)
            vi_ = hi_part ? wr : wim;      // row 2f+1 (yi)
        }
        B2[(size_t)(2 * f) * KCAT + col]     = f2b(vr);
        B2[(size_t)(2 * f + 1) * KCAT + col] = f2b(vi_);
        return;
    }
    i -= N_B2P;
    if (i < N_XP) {                 // X fp32 -> bf16, paired
        float2 v = ((const float2*)X)[i];
        *(unsigned*)(Xb + 2 * i) = pack2(v.x, v.y);
    }
}

// ---------------------------------------------------------------------------
// mag partial: magp[b][g][f] = sum over 16 channels of |Xf|; grid (32,8)
// ---------------------------------------------------------------------------
#define MAG_LD 520
__global__ void mag_kernel(const bf16* __restrict__ Xint, float* __restrict__ magp) {
    int b = blockIdx.x, g = blockIdx.y, t = threadIdx.x;
    float acc[3] = {0.0f, 0.0f, 0.0f};
    const bf16* base = Xint + ((size_t)b * 128 + g * 16) * XINT_LD;
    for (int c = 0; c < 16; c++) {
        const bf16* row = base + (size_t)c * XINT_LD;
#pragma unroll
        for (int kk = 0; kk < 3; kk++) {
            int f = t + 256 * kk;
            if (f < FB) {
                float xr = __bfloat162float(row[2 * f]);
                float xi = __bfloat162float(row[2 * f + 1]);
                acc[kk] += sqrtf(xr * xr + xi * xi);
            }
        }
    }
#pragma unroll
    for (int kk = 0; kk < 3; kk++) {
        int f = t + 256 * kk;
        if (f < FB) magp[((size_t)b * 8 + g) * MAG_LD + f] = acc[kk];
    }
}

// ---------------------------------------------------------------------------
// Fused gate + gated-bias: one block per b (256 threads).
// ---------------------------------------------------------------------------
__global__ void gate_bias_kernel(const float* __restrict__ magp, const float* __restrict__ gW,
                                 const float* __restrict__ gb, const float* __restrict__ b2r,
                                 const float* __restrict__ b2i, float* __restrict__ gate,
                                 float* __restrict__ biasC) {
    __shared__ float sred[256];
    __shared__ float sg[8];
    int b = blockIdx.x, tid = threadIdx.x;
    int e = tid & 7, j = tid >> 3;            // 32 j-groups
    float acc = 0.0f;
    for (int f = j; f < FB; f += 32) {
        float m = 0.0f;
#pragma unroll
        for (int g = 0; g < 8; g++) m += magp[((size_t)b * 8 + g) * MAG_LD + f];
        acc += m * (1.0f / 128.0f) * gW[e * FB + f];
    }
    sred[tid] = acc;
    __syncthreads();
    if (tid < 64) {
        float a = sred[tid] + sred[tid + 64] + sred[tid + 128] + sred[tid + 192];
        a += __shfl_xor(a, 8); a += __shfl_xor(a, 16); a += __shfl_xor(a, 32);
        float logit = a + gb[e];
        float mx = logit;
        mx = fmaxf(mx, __shfl_xor(mx, 1)); mx = fmaxf(mx, __shfl_xor(mx, 2)); mx = fmaxf(mx, __shfl_xor(mx, 4));
        float ex = expf(logit - mx);
        float sum = ex;
        sum += __shfl_xor(sum, 1); sum += __shfl_xor(sum, 2); sum += __shfl_xor(sum, 4);
        if (tid < 8) { float g_ = ex / sum; sg[tid] = g_; gate[b * NE + tid] = g_; }
    }
    __syncthreads();
    for (int c = tid; c < XINT_LD; c += 256) {
        float v = 0.0f;
        if (c < 2 * FB) {
            int f = c >> 1;
            const float* bb = (c & 1) ? b2i : b2r;
#pragma unroll
            for (int ee = 0; ee < NE; ee++) v += sg[ee] * bb[ee * FB + f];
        }
        biasC[b * XINT_LD + c] = v;
    }
}

// ---------------------------------------------------------------------------
// reduce fp32 planes (np=2) -> bf16 Xint, 4 cols/thread
// ---------------------------------------------------------------------------
__global__ void reduce_f32(const float* __restrict__ planes, bf16* __restrict__ outp) {
    long idx = (long)blockIdx.x * 256 + threadIdx.x;
    if (idx >= (long)MR * (XINT_LD / 4)) return;
    int c4 = (int)(idx % (XINT_LD / 4));
    long r = idx / (XINT_LD / 4);
    int c0 = c4 * 4;
    size_t base = (size_t)r * XINT_LD + c0;
    float4 a = *(const float4*)(planes + base);
    float4 b = *(const float4*)(planes + PLANE + base);
    float s[4] = {a.x + b.x, a.y + b.y, a.z + b.z, a.w + b.w};
    short4v o;
#pragma unroll
    for (int j = 0; j < 4; j++) o[j] = (short)f2bu((c0 + j < 2 * FB) ? s[j] : 0.0f);
    *(short4v*)(outp + base) = o;
}

// ---------------------------------------------------------------------------
// reduce bf16 planes (np=4) + biasC -> bf16 combb, 8 cols/thread
// ---------------------------------------------------------------------------
__global__ void reduce_bf(const bf16* __restrict__ planes, const float* __restrict__ biasC,
                          bf16* __restrict__ outp) {
    long idx = (long)blockIdx.x * 256 + threadIdx.x;
    if (idx >= (long)MR * (XINT_LD / 8)) return;
    int c8 = (int)(idx % (XINT_LD / 8));
    long r = idx / (XINT_LD / 8);
    int c0 = c8 * 8;
    size_t base = (size_t)r * XINT_LD + c0;
    float s[8] = {};
#pragma unroll
    for (int z = 0; z < 4; z++) {
        short8 v = *(const short8*)(planes + (size_t)z * PLANE + base);
#pragma unroll
        for (int j = 0; j < 8; j++) s[j] += bu2f((unsigned short)v[j]);
    }
    const float* bC = biasC + ((int)(r >> 7)) * XINT_LD + c0;
    short8 o;
#pragma unroll
    for (int j = 0; j < 8; j++) {
        float val = (c0 + j < 2 * FB) ? (s[j] + bC[j]) : 0.0f;
        o[j] = (short)f2bu(val);
    }
    *(short8*)(outp + base) = o;
}

// ---------------------------------------------------------------------------
// reduce fp32 out planes (np=2) -> f32 out, 4/thread
// ---------------------------------------------------------------------------
__global__ void reduce_out(const float* __restrict__ planes, float* __restrict__ out) {
    long idx = (long)blockIdx.x * 256 + threadIdx.x;
    if (idx >= (long)MR * NN / 4) return;
    size_t base = (size_t)idx * 4;
    float4 a = *(const float4*)(planes + base);
    float4 b = *(const float4*)(planes + (size_t)MR * NN + base);
    float4 o = {a.x + b.x, a.y + b.y, a.z + b.z, a.w + b.w};
    *(float4*)(out + base) = o;
}

// ---------------------------------------------------------------------------
// MFMA GEMM: C = A[4096][K]*B[N][K]^T (bf16 in, fp32 acc). 128x128 tile, BK=32,
// 4 waves, 4x4 mfma_f32_16x16x32_bf16. XCD-swizzled block mapping.
// EPI 0: bf16 store to plane z (K-range z*kPerZ..)
// EPI 1: per-z expert: K-range from se2[2z..], v=relu(acc+bias)*gate -> bf16
// EPI 3: f32 store to plane z (K-range z*kPerZ..)
// ---------------------------------------------------------------------------
template <int EPI>
__global__ void gemm_mfma(const bf16* __restrict__ A, int lda,
                          const bf16* __restrict__ B, int ldb, size_t zBstride,
                          void* __restrict__ Cv, int ldc, size_t zCoff,
                          int N, int K, int kPerZ,
                          const int* __restrict__ se2,
                          const float* __restrict__ biasR, const float* __restrict__ biasI,
                          int zBias, const float* __restrict__ gate8) {
    __shared__ bf16 As[128 * 32];
    __shared__ bf16 Bs[128 * 32];
    int tid = threadIdx.x;
    int zz = blockIdx.z;
    int bx, by;
    xcd_swizzle(&bx, &by);
    int row0 = by * 128, col0 = bx * 128;
    const bf16* Bz = B + (size_t)zz * zBstride;

    int kS, kE;
    if (EPI == 1) { int s = se2[2 * zz], e = se2[2 * zz + 1]; kS = (2 * s) & ~31; kE = (2 * e + 31) & ~31; }
    else          { kS = zz * kPerZ; kE = min(K, kS + kPerZ); }

    f32x4 acc[4][4] = {};

    int lane = tid & 63, wid = tid >> 6;
    int wrB = (wid >> 1) << 6, wcB = (wid & 1) << 6;
    int lr = lane & 15, lk = (lane >> 4) << 3;

    int r_a = tid >> 2, c_a = (tid & 3) << 3;
    int r_b = (tid + 256) >> 2, c_b = ((tid + 256) & 3) << 3;

    for (int kt = kS; kt < kE; kt += 32) {
        gload16(A + (size_t)(row0 + r_a) * lda + kt + c_a, &As[(size_t)tid * 8]);
        gload16(A + (size_t)(row0 + r_b) * lda + kt + c_b, &As[((size_t)tid + 256) * 8]);
        gload16(Bz + (size_t)(col0 + r_a) * ldb + kt + c_a, &Bs[(size_t)tid * 8]);
        gload16(Bz + (size_t)(col0 + r_b) * ldb + kt + c_b, &Bs[((size_t)tid + 256) * 8]);
        __syncthreads();
        short8 av[4], bv[4];
#pragma unroll
        for (int m = 0; m < 4; m++)
            av[m] = *(const short8*)&As[(wrB + m * 16 + lr) * 32 + lk];
#pragma unroll
        for (int n = 0; n < 4; n++)
            bv[n] = *(const short8*)&Bs[(wcB + n * 16 + lr) * 32 + lk];
#pragma unroll
        for (int m = 0; m < 4; m++)
#pragma unroll
            for (int n = 0; n < 4; n++)
                acc[m][n] = __builtin_amdgcn_mfma_f32_16x16x32_bf16(av[m], bv[n], acc[m][n], 0, 0, 0);
        __syncthreads();
    }

    int r0 = row0 + wrB + ((lane >> 4) << 2);
    int c0i = col0 + wcB + (lane & 15);
    float g = (EPI == 1) ? gate8[(row0 >> 7) * NE + zz] : 0.0f;

#pragma unroll
    for (int m = 0; m < 4; m++)
#pragma unroll
        for (int n = 0; n < 4; n++) {
            int c = c0i + n * 16;
            if (c >= N) continue;
#pragma unroll
            for (int j = 0; j < 4; j++) {
                int r = r0 + m * 16 + j;
                float v = acc[m][n][j];
                if (EPI == 0) {
                    ((bf16*)Cv + (size_t)zz * zCoff)[(size_t)r * ldc + c] = f2b(v);
                } else if (EPI == 1) {
                    v += (c < HD) ? biasR[zz * zBias + c] : biasI[zz * zBias + c - HD];
                    v = fmaxf(v, 0.0f) * g;
                    ((bf16*)Cv + (size_t)zz * zCoff)[(size_t)r * ldc + c] = f2b(v);
                } else {
                    ((float*)Cv + (size_t)zz * zCoff)[(size_t)r * ldc + c] = v;
                }
            }
        }
}

// ---------------------------------------------------------------------------
extern "C" void kernel_launch(void* const* d_in, const int* in_sizes, int n_in,
                              void* d_out, int out_size, void* d_ws, size_t ws_size,
                              hipStream_t stream) {
    const float* X   = (const float*)d_in[0];
    const float* bp  = (const float*)d_in[1];
    const float* W1r = (const float*)d_in[2];
    const float* W1i = (const float*)d_in[3];
    const float* b1r = (const float*)d_in[4];
    const float* b1i = (const float*)d_in[5];
    const float* W2r = (const float*)d_in[6];
    const float* W2i = (const float*)d_in[7];
    const float* b2r = (const float*)d_in[8];
    const float* b2i = (const float*)d_in[9];
    const float* gW  = (const float*)d_in[10];
    const float* gb  = (const float*)d_in[11];
    float* out = (float*)d_out;

    const size_t SZH = (size_t)MR * HP_LD * 2;           // 17,039,360
    const size_t PARTIAL_BYTES = 2 * PLANE * 4;          // 34,603,008 (2 f32 = 4 bf16 planes)

    // ---- carve workspace
    char* wsb = (char*)d_ws;
    char* p = wsb;
    auto alloc = [&](size_t bytes) -> char* {
        char* r = p; p += (bytes + 255) & ~255ULL; return r;
    };
    int*   se    = (int*)alloc(64 * 4);
    float* magp  = (float*)alloc((size_t)BATCH * 8 * MAG_LD * 4);
    float* gate  = (float*)alloc((size_t)BATCH * NE * 4);
    float* biasC = (float*)alloc((size_t)BATCH * XINT_LD * 4);
    bf16*  Ffwd  = (bf16*)alloc(1056 * 1024 * 2);
    bf16*  Finv  = (bf16*)alloc((size_t)NN * XINT_LD * 2);
    bf16*  B1    = (bf16*)alloc((size_t)NE * B1_ROWS * XINT_LD * 2);
    bf16*  B2    = (bf16*)alloc((size_t)B2_ROWS * KCAT * 2);
    bf16*  Xint  = (bf16*)alloc(PLANE * 2);
    bf16*  combb = (bf16*)alloc(PLANE * 2);
    char*  partialSlot = alloc(PARTIAL_BYTES);
    float* partialF = (float*)partialSlot;
    bf16*  partialB = (bf16*)partialSlot;

    size_t used = (size_t)(p - wsb);
    int chunk = (used + 8 * SZH <= ws_size) ? 8 : 4;     // tier A / tier B
    bf16* Hp = (bf16*)alloc((size_t)chunk * SZH);
    // Xb lives in the tail of Hp (dead after the DFT; L1 overwrites later;
    // any residue in Hp pad cols multiplies B2's zero pad cols -> inert)
    bf16* Xb = (bf16*)((char*)Hp + (size_t)chunk * SZH - (size_t)MR * NN * 2);

    // ---- prep: bounds, then fused tables/packing/convert
    prep_kernel<<<1, 64, 0, stream>>>(bp, se);
    prep_bulk<<<(unsigned)((N_PREP + 255) / 256), 256, 0, stream>>>(
        W1r, W1i, W2r, W2i, X, se, Ffwd, Finv, B1, B2, Xb);

    // ---- forward DFT: Xint = Xb * Ffwd^T  (split-K 2, fp32 partials)
    gemm_mfma<3><<<dim3(9, 32, 2), 256, 0, stream>>>(
        Xb, NN, Ffwd, NN, 0, partialF, XINT_LD, PLANE,
        1056, NN, 512, nullptr, nullptr, nullptr, 0, nullptr);
    reduce_f32<<<(unsigned)(((size_t)MR * (XINT_LD / 4) + 255) / 256), 256, 0, stream>>>(
        partialF, Xint);

    // ---- gate path
    mag_kernel<<<dim3(BATCH, 8), 256, 0, stream>>>(Xint, magp);
    gate_bias_kernel<<<BATCH, 256, 0, stream>>>(magp, gW, gb, b2r, b2i, gate, biasC);

    // ---- L1 (gate folded) then L2 (K-concat, split-K into bf16 planes)
    int nch = NE / chunk;
    for (int ci = 0; ci < nch; ci++) {
        int e0 = ci * chunk;
        gemm_mfma<1><<<dim3(17, 32, chunk), 256, 0, stream>>>(
            Xint, XINT_LD,
            B1 + (size_t)e0 * B1_ROWS * XINT_LD, XINT_LD, (size_t)B1_ROWS * XINT_LD,
            Hp, chunk * HP_LD, HP_LD,
            2 * HD, 0, 0,
            se + 2 * e0, b1r + (size_t)e0 * HD, b1i + (size_t)e0 * HD, HD, gate + e0);

        int Kc = chunk * HP_LD;
        int zsplit = (chunk == 8) ? 4 : 2;               // kPerZ = 4160 both tiers
        int kPerZ = Kc / zsplit;
        gemm_mfma<0><<<dim3(9, 32, zsplit), 256, 0, stream>>>(
            Hp, Kc, B2 + (size_t)e0 * HP_LD, KCAT, 0,
            partialB + (size_t)(ci * zsplit) * PLANE, XINT_LD, PLANE,
            2 * FB, Kc, kPerZ, nullptr, nullptr, nullptr, 0, nullptr);
    }

    // ---- reduce 4 bf16 planes + gated bias -> bf16 combb
    reduce_bf<<<(unsigned)(((size_t)MR * (XINT_LD / 8) + 255) / 256), 256, 0, stream>>>(
        partialB, biasC, combb);

    // ---- inverse DFT: out = combb * Finv^T (split-K 2, fp32 partials)
    gemm_mfma<3><<<dim3(8, 32, 2), 256, 0, stream>>>(
        combb, XINT_LD, Finv, XINT_LD, 0, partialF, NN, (size_t)MR * NN,
        NN, XINT_LD, 544, nullptr, nullptr, nullptr, 0, nullptr);
    reduce_out<<<(unsigned)(((size_t)MR * NN / 4 + 255) / 256), 256, 0, stream>>>(
        partialF, out);
}